// Round 6
// baseline (885.614 us; speedup 1.0000x reference)
//
#include <hip/hip_runtime.h>
#include <math.h>

#define HIDDEN 1024
#define HEAD_DIM 64
#define NEXP 16
#define NTOK 8192          // B*T
#define SEQ 2048
#define NB 4

// ---------------- workspace layout (bytes) — 9.96MB envelope, proven safe ----------------
#define OFF_PREP   0
#define OFF_CNT    256
#define OFF_TOK    512
#define OFF_WGT    (OFF_TOK + 524288)
#define OFF_RW     (OFF_WGT + 524288)
#define OFF_Q      (OFF_RW + 524288)
#define OFF_K      (OFF_Q + 2097152)
#define OFF_V      (OFF_K + 2097152)
#define OFF_ATTN   (OFF_V + 2097152)

// ---------------- prep: sim column inv-norms + sigmoid(gates) ----------------
__global__ __launch_bounds__(256) void prep_kernel(const float* __restrict__ sim,
                                                   const float* __restrict__ gates,
                                                   float* __restrict__ prep) {
    int tid = threadIdx.x;
    int e = tid & 15, part = tid >> 4;
    float ss = 0.f;
    for (int c = part; c < HIDDEN; c += 16) {
        float v = sim[c * NEXP + e];
        ss += v * v;
    }
    __shared__ float red[16][17];
    red[part][e] = ss;
    __syncthreads();
    if (tid < 16) {
        float s = 0.f;
        #pragma unroll
        for (int p = 0; p < 16; ++p) s += red[p][tid];
        prep[tid] = 1.f / fmaxf(sqrtf(s), 1e-12f);
        prep[16 + tid] = 1.f / (1.f + expf(-gates[tid]));
    }
}

// ---------------- gating: rw + expert-major lists + dense rw ----------------
__global__ __launch_bounds__(256) void gating_kernel(const float* __restrict__ h,
                                                     const float* __restrict__ sim,
                                                     const float* __restrict__ prep,
                                                     int* __restrict__ counts,
                                                     int* __restrict__ tok_list,
                                                     float* __restrict__ wgt_list,
                                                     float* __restrict__ rw_dense) {
    int t = blockIdx.x;
    int tid = threadIdx.x;
    const float* hrow = h + (size_t)t * HIDDEN;
    float dot[16];
    #pragma unroll
    for (int e = 0; e < 16; ++e) dot[e] = 0.f;
    float ss = 0.f;
    for (int c = tid; c < HIDDEN; c += 256) {
        float hv = hrow[c];
        ss += hv * hv;
        const float4* s4 = (const float4*)(sim + c * NEXP);
        float4 a = s4[0], b = s4[1], cc = s4[2], d = s4[3];
        dot[0]  += hv * a.x;  dot[1]  += hv * a.y;  dot[2]  += hv * a.z;  dot[3]  += hv * a.w;
        dot[4]  += hv * b.x;  dot[5]  += hv * b.y;  dot[6]  += hv * b.z;  dot[7]  += hv * b.w;
        dot[8]  += hv * cc.x; dot[9]  += hv * cc.y; dot[10] += hv * cc.z; dot[11] += hv * cc.w;
        dot[12] += hv * d.x;  dot[13] += hv * d.y;  dot[14] += hv * d.z;  dot[15] += hv * d.w;
    }
    int lane = tid & 63, wv = tid >> 6;
    #pragma unroll
    for (int off = 32; off > 0; off >>= 1) {
        ss += __shfl_down(ss, off, 64);
        #pragma unroll
        for (int e = 0; e < 16; ++e) dot[e] += __shfl_down(dot[e], off, 64);
    }
    __shared__ float red[4][17];
    if (lane == 0) {
        red[wv][16] = ss;
        #pragma unroll
        for (int e = 0; e < 16; ++e) red[wv][e] = dot[e];
    }
    __syncthreads();
    if (tid == 0) {
        float tss = 0.f;
        float td[16];
        #pragma unroll
        for (int e = 0; e < 16; ++e) td[e] = 0.f;
        for (int w = 0; w < 4; ++w) {
            tss += red[w][16];
            #pragma unroll
            for (int e = 0; e < 16; ++e) td[e] += red[w][e];
        }
        float invh = 1.f / fmaxf(sqrtf(tss), 1e-12f);
        float logits[16], gated[16];
        bool mask[16];
        int nact = 0;
        #pragma unroll
        for (int e = 0; e < 16; ++e) {
            logits[e] = td[e] * invh * prep[e] - prep[16 + e];
            gated[e] = fmaxf(logits[e], 0.f);
            mask[e] = logits[e] > 0.f;
            if (mask[e]) nact++;
        }
        if (nact == 0) {
            int i1 = 0; float v1 = logits[0];
            for (int e = 1; e < 16; ++e) if (logits[e] > v1) { v1 = logits[e]; i1 = e; }
            int i2 = -1; float v2 = -INFINITY;
            for (int e = 0; e < 16; ++e) if (e != i1 && logits[e] > v2) { v2 = logits[e]; i2 = e; }
            mask[i1] = true; mask[i2] = true;
        }
        float m = -INFINITY;
        #pragma unroll
        for (int e = 0; e < 16; ++e) if (mask[e]) m = fmaxf(m, gated[e]);
        float sum = 0.f;
        float p[16];
        #pragma unroll
        for (int e = 0; e < 16; ++e) {
            p[e] = mask[e] ? expf(gated[e] - m) : 0.f;
            sum += p[e];
        }
        float inv = 1.f / sum;
        for (int e = 0; e < 16; ++e) {
            if (mask[e]) {
                float w = p[e] * inv;
                rw_dense[(size_t)t * 16 + e] = w;
                int pos = atomicAdd(&counts[e], 1);
                tok_list[e * NTOK + pos] = t;
                wgt_list[e * NTOK + pos] = w;
            } else {
                rw_dense[(size_t)t * 16 + e] = 0.f;
            }
        }
    }
}

// ---------------- fused q/k/v expert GEMM: h staged once, atomic scatter-add ----------------
// grid.x = 16 experts * 128 chunks; block 256
__global__ __launch_bounds__(256) void expert_qkv_v3(const float* __restrict__ h,
                                                     const float* __restrict__ qw,
                                                     const float* __restrict__ kw,
                                                     const float* __restrict__ vw,
                                                     const int* __restrict__ counts,
                                                     const int* __restrict__ tok_list,
                                                     const float* __restrict__ wgt_list,
                                                     float* __restrict__ qb,
                                                     float* __restrict__ kb,
                                                     float* __restrict__ vb) {
    int e = blockIdx.x >> 7, chunk = blockIdx.x & 127;
    int cnt = counts[e];
    int base = chunk * 64;
    if (base >= cnt) return;
    const float* W0 = qw + (size_t)e * HIDDEN * HEAD_DIM;
    const float* W1 = kw + (size_t)e * HIDDEN * HEAD_DIM;
    const float* W2 = vw + (size_t)e * HIDDEN * HEAD_DIM;

    __shared__ int s_tok[64];
    __shared__ float s_wt[64];
    __shared__ float h_s[64][36];      // [token][k] row-major, broadcast reads
    __shared__ float w_s[3][32][68];   // [tensor][k][d]
    int tid = threadIdx.x;
    if (tid < 64) {
        int idx = base + tid;
        s_tok[tid] = idx < cnt ? tok_list[e * NTOK + idx] : -1;
        s_wt[tid] = idx < cnt ? wgt_list[e * NTOK + idx] : 0.f;
    }
    __syncthreads();
    int tokl = tid >> 2, q4 = tid & 3;
    int tg = tid >> 4, dg = tid & 15;
    int tok_stage = s_tok[tokl];
    const float* hrow = h + (size_t)(tok_stage >= 0 ? tok_stage : 0) * HIDDEN;

    float acc[3][4][4];
    #pragma unroll
    for (int tt = 0; tt < 3; ++tt)
        #pragma unroll
        for (int i = 0; i < 4; ++i)
            #pragma unroll
            for (int j = 0; j < 4; ++j) acc[tt][i][j] = 0.f;

    for (int kt = 0; kt < 32; ++kt) {
        __syncthreads();
        // stage h tile 64 tok x 32 ch, row-major
        #pragma unroll
        for (int r = 0; r < 2; ++r) {
            int c = (q4 + r * 4) * 4;
            float4 hv = make_float4(0.f, 0.f, 0.f, 0.f);
            if (tok_stage >= 0) hv = *(const float4*)&hrow[kt * 32 + c];
            *(float4*)&h_s[tokl][c] = hv;
        }
        // stage 3 weight tiles 32 k x 64 d
        #pragma unroll
        for (int r = 0; r < 6; ++r) {
            int idx = r * 256 + tid;
            int tt = idx >> 9;
            int rem = idx & 511;
            int k = rem >> 4, c4 = (rem & 15) * 4;
            const float* Wt = tt == 0 ? W0 : tt == 1 ? W1 : W2;
            *(float4*)&w_s[tt][k][c4] = *(const float4*)&Wt[(size_t)(kt * 32 + k) * HEAD_DIM + c4];
        }
        __syncthreads();
        #pragma unroll 4
        for (int k2 = 0; k2 < 32; ++k2) {
            float a0 = h_s[tg * 4 + 0][k2];
            float a1 = h_s[tg * 4 + 1][k2];
            float a2 = h_s[tg * 4 + 2][k2];
            float a3 = h_s[tg * 4 + 3][k2];
            #pragma unroll
            for (int tt = 0; tt < 3; ++tt) {
                float4 b = *(float4*)&w_s[tt][k2][dg * 4];
                acc[tt][0][0] += a0 * b.x; acc[tt][0][1] += a0 * b.y; acc[tt][0][2] += a0 * b.z; acc[tt][0][3] += a0 * b.w;
                acc[tt][1][0] += a1 * b.x; acc[tt][1][1] += a1 * b.y; acc[tt][1][2] += a1 * b.z; acc[tt][1][3] += a1 * b.w;
                acc[tt][2][0] += a2 * b.x; acc[tt][2][1] += a2 * b.y; acc[tt][2][2] += a2 * b.z; acc[tt][2][3] += a2 * b.w;
                acc[tt][3][0] += a3 * b.x; acc[tt][3][1] += a3 * b.y; acc[tt][3][2] += a3 * b.z; acc[tt][3][3] += a3 * b.w;
            }
        }
    }
    // epilogue: weighted atomic scatter-add (proven-correct round-2 semantics)
    #pragma unroll
    for (int i = 0; i < 4; ++i) {
        int r = tg * 4 + i;
        int tok = s_tok[r];
        if (tok >= 0) {
            float wgt = s_wt[r];
            size_t off = (size_t)tok * HEAD_DIM + dg * 4;
            #pragma unroll
            for (int j = 0; j < 4; ++j) {
                atomicAdd(&qb[off + j], wgt * acc[0][i][j]);
                atomicAdd(&kb[off + j], wgt * acc[1][i][j]);
                atomicAdd(&vb[off + j], wgt * acc[2][i][j]);
            }
        }
    }
}

// ---------------- flash causal attention, fp32 ----------------
__global__ __launch_bounds__(256) void attn_kernel(const float* __restrict__ q,
                                                   const float* __restrict__ k,
                                                   const float* __restrict__ v,
                                                   float* __restrict__ o) {
    int b = blockIdx.y;
    int q0 = blockIdx.x * 32;
    int tid = threadIdx.x;
    int row = tid & 31, grp = tid >> 5;
    int qg = q0 + row;

    __shared__ float k_s[64][68];
    __shared__ float v_s[64][68];
    __shared__ float p_s[32][68];
    __shared__ float red[8][32];

    float4 qv[16];
    const float* qrow = q + ((size_t)(b * SEQ + qg)) * HEAD_DIM;
    #pragma unroll
    for (int i = 0; i < 16; ++i) qv[i] = *(const float4*)(qrow + i * 4);

    float acc[8];
    #pragma unroll
    for (int i = 0; i < 8; ++i) acc[i] = 0.f;
    float m = -INFINITY, l = 0.f;

    int nkt = (q0 + 32 + 63) >> 6;
    int kr = tid >> 2, dg4 = (tid & 3) * 16;
    int k0 = grp * 8;

    for (int kt = 0; kt < nkt; ++kt) {
        __syncthreads();
        {
            const float* krg = k + ((size_t)(b * SEQ + kt * 64 + kr)) * HEAD_DIM + dg4;
            const float* vrg = v + ((size_t)(b * SEQ + kt * 64 + kr)) * HEAD_DIM + dg4;
            #pragma unroll
            for (int r = 0; r < 4; ++r) {
                *(float4*)&k_s[kr][dg4 + r * 4] = *(const float4*)(krg + r * 4);
                *(float4*)&v_s[kr][dg4 + r * 4] = *(const float4*)(vrg + r * 4);
            }
        }
        __syncthreads();
        float s[8];
        #pragma unroll
        for (int i = 0; i < 8; ++i) s[i] = 0.f;
        #pragma unroll
        for (int d0 = 0; d0 < 16; ++d0) {
            float4 a = qv[d0];
            #pragma unroll
            for (int i = 0; i < 8; ++i) {
                float4 kk4 = *(float4*)&k_s[k0 + i][d0 * 4];
                s[i] += a.x * kk4.x + a.y * kk4.y + a.z * kk4.z + a.w * kk4.w;
            }
        }
        float pm = -INFINITY;
        #pragma unroll
        for (int i = 0; i < 8; ++i) {
            int kg = kt * 64 + k0 + i;
            s[i] = (kg <= qg) ? s[i] * 0.125f : -INFINITY;
            pm = fmaxf(pm, s[i]);
        }
        red[grp][row] = pm;
        __syncthreads();
        float tm = -INFINITY;
        #pragma unroll
        for (int g = 0; g < 8; ++g) tm = fmaxf(tm, red[g][row]);
        float mnew = fmaxf(m, tm);
        float corr = __expf(m - mnew);
        float p[8];
        float psum = 0.f;
        #pragma unroll
        for (int i = 0; i < 8; ++i) {
            p[i] = __expf(s[i] - mnew);
            psum += p[i];
        }
        __syncthreads();
        red[grp][row] = psum;
        __syncthreads();
        float tsum = 0.f;
        #pragma unroll
        for (int g = 0; g < 8; ++g) tsum += red[g][row];
        l = l * corr + tsum;
        m = mnew;
        #pragma unroll
        for (int i = 0; i < 8; ++i) p_s[row][k0 + i] = p[i];
        #pragma unroll
        for (int d = 0; d < 8; ++d) acc[d] *= corr;
        __syncthreads();
        #pragma unroll 8
        for (int k2 = 0; k2 < 64; ++k2) {
            float pv = p_s[row][k2];
            float4 v0 = *(float4*)&v_s[k2][grp * 8];
            float4 v1 = *(float4*)&v_s[k2][grp * 8 + 4];
            acc[0] += pv * v0.x; acc[1] += pv * v0.y; acc[2] += pv * v0.z; acc[3] += pv * v0.w;
            acc[4] += pv * v1.x; acc[5] += pv * v1.y; acc[6] += pv * v1.z; acc[7] += pv * v1.w;
        }
    }
    float invl = 1.f / l;
    float* orow = o + ((size_t)(b * SEQ + qg)) * HEAD_DIM + grp * 8;
    float4 o0 = make_float4(acc[0] * invl, acc[1] * invl, acc[2] * invl, acc[3] * invl);
    float4 o1 = make_float4(acc[4] * invl, acc[5] * invl, acc[6] * invl, acc[7] * invl);
    *(float4*)orow = o0;
    *(float4*)(orow + 4) = o1;
}

// ---------------- token-major output projection, LDS accumulator, NO atomics ----------------
__global__ __launch_bounds__(256) void expert_out_v2(const float* __restrict__ attn,
                                                     const float* __restrict__ ow,
                                                     const float* __restrict__ rw_dense,
                                                     float* __restrict__ out) {
    int t0 = blockIdx.x * 64;
    int c0 = blockIdx.y * 64;
    int tid = threadIdx.x;

    __shared__ float x_s[64][68];
    __shared__ float o_s[64][68];
    __shared__ float acc_s[64][68];
    __shared__ float rw_s[64][16];
    __shared__ int lst[64];
    __shared__ int lcnt;

    #pragma unroll
    for (int r = 0; r < 4; ++r) {
        int idx = r * 256 + tid;
        int t = idx >> 4, q = idx & 15;
        *(float4*)&x_s[t][q * 4] = *(const float4*)&attn[(size_t)(t0 + t) * HEAD_DIM + q * 4];
        *(float4*)&acc_s[t][q * 4] = make_float4(0.f, 0.f, 0.f, 0.f);
    }
    {
        int t = tid >> 2, eg = tid & 3;
        *(float4*)&rw_s[t][eg * 4] = *(const float4*)&rw_dense[(size_t)(t0 + t) * 16 + eg * 4];
    }
    __syncthreads();

    for (int e = 0; e < 16; ++e) {
        if (tid == 0) lcnt = 0;
        __syncthreads();
        if (tid < 64 && rw_s[tid][e] != 0.f) {
            int p = atomicAdd(&lcnt, 1);
            lst[p] = tid;
        }
        #pragma unroll
        for (int r = 0; r < 4; ++r) {
            int idx = r * 256 + tid;
            int d = idx >> 4, q = idx & 15;
            *(float4*)&o_s[d][q * 4] =
                *(const float4*)&ow[(size_t)e * HEAD_DIM * HIDDEN + (size_t)d * HIDDEN + c0 + q * 4];
        }
        __syncthreads();
        int P = lcnt;
        int pg = tid >> 4, c4 = (tid & 15) * 4;
        for (int p = pg; p < P; p += 16) {
            int t = lst[p];
            float w = rw_s[t][e];
            float sx = 0.f, sy = 0.f, sz = 0.f, sw = 0.f;
            #pragma unroll 8
            for (int d = 0; d < 64; ++d) {
                float xv = x_s[t][d];
                float4 o4 = *(float4*)&o_s[d][c4];
                sx += xv * o4.x; sy += xv * o4.y; sz += xv * o4.z; sw += xv * o4.w;
            }
            float4 a = *(float4*)&acc_s[t][c4];
            a.x += w * sx; a.y += w * sy; a.z += w * sz; a.w += w * sw;
            *(float4*)&acc_s[t][c4] = a;
        }
        __syncthreads();
    }
    #pragma unroll
    for (int r = 0; r < 4; ++r) {
        int idx = r * 256 + tid;
        int t = idx >> 4, q = idx & 15;
        *(float4*)&out[(size_t)(t0 + t) * HIDDEN + c0 + q * 4] = *(float4*)&acc_s[t][q * 4];
    }
}

extern "C" void kernel_launch(void* const* d_in, const int* in_sizes, int n_in,
                              void* d_out, int out_size, void* d_ws, size_t ws_size,
                              hipStream_t stream) {
    const float* h     = (const float*)d_in[0];
    const float* sim   = (const float*)d_in[1];
    const float* gates = (const float*)d_in[2];
    const float* qw    = (const float*)d_in[3];
    const float* kw    = (const float*)d_in[4];
    const float* vw    = (const float*)d_in[5];
    const float* ow    = (const float*)d_in[6];
    float* out = (float*)d_out;

    char* w = (char*)d_ws;
    float* prep     = (float*)(w + OFF_PREP);
    int*   counts   = (int*)(w + OFF_CNT);
    int*   tok_list = (int*)(w + OFF_TOK);
    float* wgt_list = (float*)(w + OFF_WGT);
    float* rw_dense = (float*)(w + OFF_RW);
    float* qb       = (float*)(w + OFF_Q);
    float* kb       = (float*)(w + OFF_K);
    float* vb       = (float*)(w + OFF_V);
    float* attnb    = (float*)(w + OFF_ATTN);

    hipMemsetAsync(counts, 0, 64, stream);
    hipMemsetAsync(qb, 0, 3 * 2097152, stream);   // q,k,v contiguous zero-init for atomics

    prep_kernel<<<1, 256, 0, stream>>>(sim, gates, prep);
    gating_kernel<<<NTOK, 256, 0, stream>>>(h, sim, prep, counts, tok_list, wgt_list, rw_dense);
    expert_qkv_v3<<<16 * 128, 256, 0, stream>>>(h, qw, kw, vw, counts, tok_list, wgt_list,
                                                qb, kb, vb);
    attn_kernel<<<dim3(64, 4), 256, 0, stream>>>(qb, kb, vb, attnb);
    expert_out_v2<<<dim3(128, 16), 256, 0, stream>>>(attnb, ow, rw_dense, out);
}

// Round 7
// 792.263 us; speedup vs baseline: 1.1178x; 1.1178x over previous
//
#include <hip/hip_runtime.h>
#include <math.h>

#define HIDDEN 1024
#define HEAD_DIM 64
#define NEXP 16
#define NTOK 8192          // B*T
#define SEQ 2048
#define NB 4

// ---------------- workspace layout (bytes) ----------------
#define OFF_PREP   0
#define OFF_CNT    256
#define OFF_TOK    512
#define OFF_WGT    (OFF_TOK + 524288)
#define OFF_RW     (OFF_WGT + 524288)
#define OFF_Q      (OFF_RW + 524288)
#define OFF_K      (OFF_Q + 2097152)
#define OFF_V      (OFF_K + 2097152)
#define OFF_ATTN   (OFF_V + 2097152)
// optional split-KV partials (only used if ws_size permits)
#define OFF_ACCP   (OFF_ATTN + 2097152)          // 4*4*2048*64 f32 = 8 MB
#define OFF_MLP    (OFF_ACCP + 8388608)          // 4*4*2048*2 f32 = 256 KB
#define WS_NEED_SPLIT (OFF_MLP + 262144)

// ---------------- prep: sim column inv-norms + sigmoid(gates) ----------------
__global__ __launch_bounds__(256) void prep_kernel(const float* __restrict__ sim,
                                                   const float* __restrict__ gates,
                                                   float* __restrict__ prep) {
    int tid = threadIdx.x;
    int e = tid & 15, part = tid >> 4;
    float ss = 0.f;
    for (int c = part; c < HIDDEN; c += 16) {
        float v = sim[c * NEXP + e];
        ss += v * v;
    }
    __shared__ float red[16][17];
    red[part][e] = ss;
    __syncthreads();
    if (tid < 16) {
        float s = 0.f;
        #pragma unroll
        for (int p = 0; p < 16; ++p) s += red[p][tid];
        prep[tid] = 1.f / fmaxf(sqrtf(s), 1e-12f);
        prep[16 + tid] = 1.f / (1.f + expf(-gates[tid]));
    }
}

// ---------------- gating: rw + expert-major lists + dense rw ----------------
__global__ __launch_bounds__(256) void gating_kernel(const float* __restrict__ h,
                                                     const float* __restrict__ sim,
                                                     const float* __restrict__ prep,
                                                     int* __restrict__ counts,
                                                     int* __restrict__ tok_list,
                                                     float* __restrict__ wgt_list,
                                                     float* __restrict__ rw_dense) {
    int t = blockIdx.x;
    int tid = threadIdx.x;
    const float* hrow = h + (size_t)t * HIDDEN;
    float dot[16];
    #pragma unroll
    for (int e = 0; e < 16; ++e) dot[e] = 0.f;
    float ss = 0.f;
    for (int c = tid; c < HIDDEN; c += 256) {
        float hv = hrow[c];
        ss += hv * hv;
        const float4* s4 = (const float4*)(sim + c * NEXP);
        float4 a = s4[0], b = s4[1], cc = s4[2], d = s4[3];
        dot[0]  += hv * a.x;  dot[1]  += hv * a.y;  dot[2]  += hv * a.z;  dot[3]  += hv * a.w;
        dot[4]  += hv * b.x;  dot[5]  += hv * b.y;  dot[6]  += hv * b.z;  dot[7]  += hv * b.w;
        dot[8]  += hv * cc.x; dot[9]  += hv * cc.y; dot[10] += hv * cc.z; dot[11] += hv * cc.w;
        dot[12] += hv * d.x;  dot[13] += hv * d.y;  dot[14] += hv * d.z;  dot[15] += hv * d.w;
    }
    int lane = tid & 63, wv = tid >> 6;
    #pragma unroll
    for (int off = 32; off > 0; off >>= 1) {
        ss += __shfl_down(ss, off, 64);
        #pragma unroll
        for (int e = 0; e < 16; ++e) dot[e] += __shfl_down(dot[e], off, 64);
    }
    __shared__ float red[4][17];
    if (lane == 0) {
        red[wv][16] = ss;
        #pragma unroll
        for (int e = 0; e < 16; ++e) red[wv][e] = dot[e];
    }
    __syncthreads();
    if (tid == 0) {
        float tss = 0.f;
        float td[16];
        #pragma unroll
        for (int e = 0; e < 16; ++e) td[e] = 0.f;
        for (int w = 0; w < 4; ++w) {
            tss += red[w][16];
            #pragma unroll
            for (int e = 0; e < 16; ++e) td[e] += red[w][e];
        }
        float invh = 1.f / fmaxf(sqrtf(tss), 1e-12f);
        float logits[16], gated[16];
        bool mask[16];
        int nact = 0;
        #pragma unroll
        for (int e = 0; e < 16; ++e) {
            logits[e] = td[e] * invh * prep[e] - prep[16 + e];
            gated[e] = fmaxf(logits[e], 0.f);
            mask[e] = logits[e] > 0.f;
            if (mask[e]) nact++;
        }
        if (nact == 0) {
            int i1 = 0; float v1 = logits[0];
            for (int e = 1; e < 16; ++e) if (logits[e] > v1) { v1 = logits[e]; i1 = e; }
            int i2 = -1; float v2 = -INFINITY;
            for (int e = 0; e < 16; ++e) if (e != i1 && logits[e] > v2) { v2 = logits[e]; i2 = e; }
            mask[i1] = true; mask[i2] = true;
        }
        float m = -INFINITY;
        #pragma unroll
        for (int e = 0; e < 16; ++e) if (mask[e]) m = fmaxf(m, gated[e]);
        float sum = 0.f;
        float p[16];
        #pragma unroll
        for (int e = 0; e < 16; ++e) {
            p[e] = mask[e] ? expf(gated[e] - m) : 0.f;
            sum += p[e];
        }
        float inv = 1.f / sum;
        for (int e = 0; e < 16; ++e) {
            if (mask[e]) {
                float w = p[e] * inv;
                rw_dense[(size_t)t * 16 + e] = w;
                int pos = atomicAdd(&counts[e], 1);
                tok_list[e * NTOK + pos] = t;
                wgt_list[e * NTOK + pos] = w;
            } else {
                rw_dense[(size_t)t * 16 + e] = 0.f;
            }
        }
    }
}

// ---------------- fused q/k/v expert GEMM v4: BK=16, reg-prefetch, small LDS ----------------
// grid.x = 16 experts * 128 chunks; block 256
__global__ __launch_bounds__(256) void expert_qkv_v4(const float* __restrict__ h,
                                                     const float* __restrict__ qw,
                                                     const float* __restrict__ kw,
                                                     const float* __restrict__ vw,
                                                     const int* __restrict__ counts,
                                                     const int* __restrict__ tok_list,
                                                     const float* __restrict__ wgt_list,
                                                     float* __restrict__ qb,
                                                     float* __restrict__ kb,
                                                     float* __restrict__ vb) {
    int e = blockIdx.x >> 7, chunk = blockIdx.x & 127;
    int cnt = counts[e];
    int base = chunk * 64;
    if (base >= cnt) return;
    const float* W0 = qw + (size_t)e * HIDDEN * HEAD_DIM;
    const float* W1 = kw + (size_t)e * HIDDEN * HEAD_DIM;
    const float* W2 = vw + (size_t)e * HIDDEN * HEAD_DIM;

    __shared__ int s_tok[64];
    __shared__ float s_wt[64];
    __shared__ float h_s[64][20];      // [token][k] BK=16, row-major broadcast reads
    __shared__ float w_s[3][16][68];   // [tensor][k][d]
    int tid = threadIdx.x;
    if (tid < 64) {
        int idx = base + tid;
        s_tok[tid] = idx < cnt ? tok_list[e * NTOK + idx] : -1;
        s_wt[tid] = idx < cnt ? wgt_list[e * NTOK + idx] : 0.f;
    }
    __syncthreads();
    int tokl = tid >> 2, q4 = tid & 3;          // h staging: 64 tok x (4x4 ch)
    int wk = tid >> 4, wc4 = (tid & 15) * 4;    // w staging: 16 k x 16 float4
    int tg = tid >> 4, dg = tid & 15;           // compute: 4 tok x 4 d per thread
    int tok_stage = s_tok[tokl];
    const float* hrow = h + (size_t)(tok_stage >= 0 ? tok_stage : 0) * HIDDEN;

    float acc[3][4][4];
    #pragma unroll
    for (int tt = 0; tt < 3; ++tt)
        #pragma unroll
        for (int i = 0; i < 4; ++i)
            #pragma unroll
            for (int j = 0; j < 4; ++j) acc[tt][i][j] = 0.f;

    // prefetch tile 0 into regs
    float4 ph = make_float4(0.f, 0.f, 0.f, 0.f);
    if (tok_stage >= 0) ph = *(const float4*)&hrow[q4 * 4];
    float4 pw0 = *(const float4*)&W0[(size_t)wk * HEAD_DIM + wc4];
    float4 pw1 = *(const float4*)&W1[(size_t)wk * HEAD_DIM + wc4];
    float4 pw2 = *(const float4*)&W2[(size_t)wk * HEAD_DIM + wc4];

    for (int kt = 0; kt < 64; ++kt) {
        __syncthreads();                      // prior-tile LDS reads done
        *(float4*)&h_s[tokl][q4 * 4] = ph;
        *(float4*)&w_s[0][wk][wc4] = pw0;
        *(float4*)&w_s[1][wk][wc4] = pw1;
        *(float4*)&w_s[2][wk][wc4] = pw2;
        __syncthreads();                      // stores visible
        if (kt < 63) {
            int koff = (kt + 1) * 16;
            if (tok_stage >= 0) ph = *(const float4*)&hrow[koff + q4 * 4];
            pw0 = *(const float4*)&W0[(size_t)(koff + wk) * HEAD_DIM + wc4];
            pw1 = *(const float4*)&W1[(size_t)(koff + wk) * HEAD_DIM + wc4];
            pw2 = *(const float4*)&W2[(size_t)(koff + wk) * HEAD_DIM + wc4];
        }
        #pragma unroll 4
        for (int k2 = 0; k2 < 16; ++k2) {
            float a0 = h_s[tg * 4 + 0][k2];
            float a1 = h_s[tg * 4 + 1][k2];
            float a2 = h_s[tg * 4 + 2][k2];
            float a3 = h_s[tg * 4 + 3][k2];
            #pragma unroll
            for (int tt = 0; tt < 3; ++tt) {
                float4 b = *(float4*)&w_s[tt][k2][dg * 4];
                acc[tt][0][0] += a0 * b.x; acc[tt][0][1] += a0 * b.y; acc[tt][0][2] += a0 * b.z; acc[tt][0][3] += a0 * b.w;
                acc[tt][1][0] += a1 * b.x; acc[tt][1][1] += a1 * b.y; acc[tt][1][2] += a1 * b.z; acc[tt][1][3] += a1 * b.w;
                acc[tt][2][0] += a2 * b.x; acc[tt][2][1] += a2 * b.y; acc[tt][2][2] += a2 * b.z; acc[tt][2][3] += a2 * b.w;
                acc[tt][3][0] += a3 * b.x; acc[tt][3][1] += a3 * b.y; acc[tt][3][2] += a3 * b.z; acc[tt][3][3] += a3 * b.w;
            }
        }
    }
    // epilogue: weighted atomic scatter-add (proven-correct semantics)
    #pragma unroll
    for (int i = 0; i < 4; ++i) {
        int r = tg * 4 + i;
        int tok = s_tok[r];
        if (tok >= 0) {
            float wgt = s_wt[r];
            size_t off = (size_t)tok * HEAD_DIM + dg * 4;
            #pragma unroll
            for (int j = 0; j < 4; ++j) {
                atomicAdd(&qb[off + j], wgt * acc[0][i][j]);
                atomicAdd(&kb[off + j], wgt * acc[1][i][j]);
                atomicAdd(&vb[off + j], wgt * acc[2][i][j]);
            }
        }
    }
}

// ---------------- flash causal attention, split-KV, shfl softmax ----------------
// grid (64 qtiles, nchunks, 4 batches); block 256 = 32 rows x 8 lane-groups
__global__ __launch_bounds__(256) void attn_split(const float* __restrict__ q,
                                                  const float* __restrict__ k,
                                                  const float* __restrict__ v,
                                                  float* __restrict__ o,
                                                  float* __restrict__ accp,
                                                  float* __restrict__ mlp,
                                                  int nchunks) {
    int b = blockIdx.z;
    int c = blockIdx.y;
    int q0 = blockIdx.x * 32;
    int cw = (nchunks == 1) ? SEQ : 512;
    int kbeg = c * cw;
    if (kbeg > q0) return;                 // aligned: no keys for this chunk
    int kend = min(kbeg + cw, q0 + 32);    // multiple of 32
    int nkt = (kend - kbeg) >> 5;

    int tid = threadIdx.x;
    int r = tid >> 3, g = tid & 7;         // row 0..31, group 0..7 (8 contiguous lanes/row)
    int qg = q0 + r;

    __shared__ float k_s[32][68];
    __shared__ float v_s[32][68];

    // q row in regs
    float4 qv[16];
    const float* qrow = q + ((size_t)(b * SEQ + qg)) * HEAD_DIM;
    #pragma unroll
    for (int i = 0; i < 16; ++i) qv[i] = *(const float4*)(qrow + i * 4);

    float acc[8];
    #pragma unroll
    for (int i = 0; i < 8; ++i) acc[i] = 0.f;
    float m = -INFINITY, l = 0.f;

    // staging: thread stages K/V row r (of 32) cols g*8..+7 (2 float4 each)
    const float* kp = k + ((size_t)(b * SEQ + kbeg + r)) * HEAD_DIM + g * 8;
    const float* vp = v + ((size_t)(b * SEQ + kbeg + r)) * HEAD_DIM + g * 8;
    float4 pk0 = *(const float4*)kp,       pk1 = *(const float4*)(kp + 4);
    float4 pv0 = *(const float4*)vp,       pv1 = *(const float4*)(vp + 4);

    for (int kt = 0; kt < nkt; ++kt) {
        __syncthreads();                    // prior-tile LDS reads done
        *(float4*)&k_s[r][g * 8] = pk0;  *(float4*)&k_s[r][g * 8 + 4] = pk1;
        *(float4*)&v_s[r][g * 8] = pv0;  *(float4*)&v_s[r][g * 8 + 4] = pv1;
        __syncthreads();
        if (kt + 1 < nkt) {
            const float* kn = kp + (size_t)(kt + 1) * 32 * HEAD_DIM;
            const float* vn = vp + (size_t)(kt + 1) * 32 * HEAD_DIM;
            pk0 = *(const float4*)kn; pk1 = *(const float4*)(kn + 4);
            pv0 = *(const float4*)vn; pv1 = *(const float4*)(vn + 4);
        }
        // QK: this thread scores keys g*4..g*4+3 of the tile for its row
        float s[4] = {0.f, 0.f, 0.f, 0.f};
        #pragma unroll
        for (int d4 = 0; d4 < 16; ++d4) {
            float4 a = qv[d4];
            #pragma unroll
            for (int j = 0; j < 4; ++j) {
                float4 kk4 = *(float4*)&k_s[g * 4 + j][d4 * 4];
                s[j] += a.x * kk4.x + a.y * kk4.y + a.z * kk4.z + a.w * kk4.w;
            }
        }
        float pm = -INFINITY;
        #pragma unroll
        for (int j = 0; j < 4; ++j) {
            int key = kbeg + kt * 32 + g * 4 + j;
            s[j] = (key <= qg) ? s[j] * 0.125f : -INFINITY;
            pm = fmaxf(pm, s[j]);
        }
        // row reduce over 8 contiguous lanes (no LDS, no barrier)
        pm = fmaxf(pm, __shfl_xor(pm, 1, 64));
        pm = fmaxf(pm, __shfl_xor(pm, 2, 64));
        pm = fmaxf(pm, __shfl_xor(pm, 4, 64));
        float mnew = fmaxf(m, pm);          // finite: tile 0 always has key kbeg<=qg
        float corr = __expf(m - mnew);
        float p[4];
        float psum = 0.f;
        #pragma unroll
        for (int j = 0; j < 4; ++j) {
            p[j] = __expf(s[j] - mnew);
            psum += p[j];
        }
        psum += __shfl_xor(psum, 1, 64);
        psum += __shfl_xor(psum, 2, 64);
        psum += __shfl_xor(psum, 4, 64);
        l = l * corr + psum;
        m = mnew;
        #pragma unroll
        for (int d = 0; d < 8; ++d) acc[d] *= corr;
        // PV: broadcast p across the row's 8 lanes via shfl, no LDS P tile
        #pragma unroll
        for (int kk = 0; kk < 32; ++kk) {
            float pb = __shfl(p[kk & 3], (r << 3) | (kk >> 2), 64);
            float4 v0 = *(float4*)&v_s[kk][g * 8];
            float4 v1 = *(float4*)&v_s[kk][g * 8 + 4];
            acc[0] += pb * v0.x; acc[1] += pb * v0.y; acc[2] += pb * v0.z; acc[3] += pb * v0.w;
            acc[4] += pb * v1.x; acc[5] += pb * v1.y; acc[6] += pb * v1.z; acc[7] += pb * v1.w;
        }
    }

    if (nchunks == 1) {
        float invl = 1.f / l;
        float* orow = o + ((size_t)(b * SEQ + qg)) * HEAD_DIM + g * 8;
        *(float4*)orow = make_float4(acc[0] * invl, acc[1] * invl, acc[2] * invl, acc[3] * invl);
        *(float4*)(orow + 4) = make_float4(acc[4] * invl, acc[5] * invl, acc[6] * invl, acc[7] * invl);
    } else {
        size_t pidx = ((size_t)(c * NB + b) * SEQ + qg);
        float* arow = accp + pidx * HEAD_DIM + g * 8;
        *(float4*)arow = make_float4(acc[0], acc[1], acc[2], acc[3]);
        *(float4*)(arow + 4) = make_float4(acc[4], acc[5], acc[6], acc[7]);
        if (g == 0) { mlp[pidx * 2] = m; mlp[pidx * 2 + 1] = l; }
    }
}

// ---------------- combine split-KV partials ----------------
// grid 2048, block 256 = 4 rows x 64 dims
__global__ __launch_bounds__(256) void attn_combine(const float* __restrict__ accp,
                                                    const float* __restrict__ mlp,
                                                    float* __restrict__ o) {
    int gr = blockIdx.x * 4 + (threadIdx.x >> 6);   // global row 0..8191
    int d = threadIdx.x & 63;
    int b = gr >> 11, row = gr & 2047;
    int nact = (row >> 9) + 1;
    float M = -INFINITY;
    for (int c = 0; c < nact; ++c)
        M = fmaxf(M, mlp[(((size_t)(c * NB + b) * SEQ) + row) * 2]);
    float L = 0.f, A = 0.f;
    for (int c = 0; c < nact; ++c) {
        size_t pidx = ((size_t)(c * NB + b) * SEQ) + row;
        float ec = __expf(mlp[pidx * 2] - M);
        L += mlp[pidx * 2 + 1] * ec;
        A += accp[pidx * HEAD_DIM + d] * ec;
    }
    o[((size_t)(b * SEQ) + row) * HEAD_DIM + d] = A / L;
}

// ---------------- token-major output projection, LDS accumulator, NO atomics ----------------
__global__ __launch_bounds__(256) void expert_out_v2(const float* __restrict__ attn,
                                                     const float* __restrict__ ow,
                                                     const float* __restrict__ rw_dense,
                                                     float* __restrict__ out) {
    int t0 = blockIdx.x * 64;
    int c0 = blockIdx.y * 64;
    int tid = threadIdx.x;

    __shared__ float x_s[64][68];
    __shared__ float o_s[64][68];
    __shared__ float acc_s[64][68];
    __shared__ float rw_s[64][16];
    __shared__ int lst[64];
    __shared__ int lcnt;

    #pragma unroll
    for (int r = 0; r < 4; ++r) {
        int idx = r * 256 + tid;
        int t = idx >> 4, q = idx & 15;
        *(float4*)&x_s[t][q * 4] = *(const float4*)&attn[(size_t)(t0 + t) * HEAD_DIM + q * 4];
        *(float4*)&acc_s[t][q * 4] = make_float4(0.f, 0.f, 0.f, 0.f);
    }
    {
        int t = tid >> 2, eg = tid & 3;
        *(float4*)&rw_s[t][eg * 4] = *(const float4*)&rw_dense[(size_t)(t0 + t) * 16 + eg * 4];
    }
    __syncthreads();

    for (int e = 0; e < 16; ++e) {
        if (tid == 0) lcnt = 0;
        __syncthreads();
        if (tid < 64 && rw_s[tid][e] != 0.f) {
            int p = atomicAdd(&lcnt, 1);
            lst[p] = tid;
        }
        #pragma unroll
        for (int r = 0; r < 4; ++r) {
            int idx = r * 256 + tid;
            int d = idx >> 4, q = idx & 15;
            *(float4*)&o_s[d][q * 4] =
                *(const float4*)&ow[(size_t)e * HEAD_DIM * HIDDEN + (size_t)d * HIDDEN + c0 + q * 4];
        }
        __syncthreads();
        int P = lcnt;
        int pg = tid >> 4, c4 = (tid & 15) * 4;
        for (int p = pg; p < P; p += 16) {
            int t = lst[p];
            float w = rw_s[t][e];
            float sx = 0.f, sy = 0.f, sz = 0.f, sw = 0.f;
            #pragma unroll 8
            for (int d = 0; d < 64; ++d) {
                float xv = x_s[t][d];
                float4 o4 = *(float4*)&o_s[d][c4];
                sx += xv * o4.x; sy += xv * o4.y; sz += xv * o4.z; sw += xv * o4.w;
            }
            float4 a = *(float4*)&acc_s[t][c4];
            a.x += w * sx; a.y += w * sy; a.z += w * sz; a.w += w * sw;
            *(float4*)&acc_s[t][c4] = a;
        }
        __syncthreads();
    }
    #pragma unroll
    for (int r = 0; r < 4; ++r) {
        int idx = r * 256 + tid;
        int t = idx >> 4, q = idx & 15;
        *(float4*)&out[(size_t)(t0 + t) * HIDDEN + c0 + q * 4] = *(float4*)&acc_s[t][q * 4];
    }
}

extern "C" void kernel_launch(void* const* d_in, const int* in_sizes, int n_in,
                              void* d_out, int out_size, void* d_ws, size_t ws_size,
                              hipStream_t stream) {
    const float* h     = (const float*)d_in[0];
    const float* sim   = (const float*)d_in[1];
    const float* gates = (const float*)d_in[2];
    const float* qw    = (const float*)d_in[3];
    const float* kw    = (const float*)d_in[4];
    const float* vw    = (const float*)d_in[5];
    const float* ow    = (const float*)d_in[6];
    float* out = (float*)d_out;

    char* w = (char*)d_ws;
    float* prep     = (float*)(w + OFF_PREP);
    int*   counts   = (int*)(w + OFF_CNT);
    int*   tok_list = (int*)(w + OFF_TOK);
    float* wgt_list = (float*)(w + OFF_WGT);
    float* rw_dense = (float*)(w + OFF_RW);
    float* qb       = (float*)(w + OFF_Q);
    float* kb       = (float*)(w + OFF_K);
    float* vb       = (float*)(w + OFF_V);
    float* attnb    = (float*)(w + OFF_ATTN);
    float* accp     = (float*)(w + OFF_ACCP);
    float* mlp      = (float*)(w + OFF_MLP);

    hipMemsetAsync(counts, 0, 64, stream);
    hipMemsetAsync(qb, 0, 3 * 2097152, stream);   // q,k,v contiguous zero-init for atomics

    prep_kernel<<<1, 256, 0, stream>>>(sim, gates, prep);
    gating_kernel<<<NTOK, 256, 0, stream>>>(h, sim, prep, counts, tok_list, wgt_list, rw_dense);
    expert_qkv_v4<<<16 * 128, 256, 0, stream>>>(h, qw, kw, vw, counts, tok_list, wgt_list,
                                                qb, kb, vb);
    if (ws_size >= (size_t)WS_NEED_SPLIT) {
        attn_split<<<dim3(64, 4, NB), 256, 0, stream>>>(qb, kb, vb, attnb, accp, mlp, 4);
        attn_combine<<<2048, 256, 0, stream>>>(accp, mlp, attnb);
    } else {
        attn_split<<<dim3(64, 1, NB), 256, 0, stream>>>(qb, kb, vb, attnb, attnb, attnb, 1);
    }
    expert_out_v2<<<dim3(128, 16), 256, 0, stream>>>(attnb, ow, rw_dense, out);
}

// Round 8
// 764.658 us; speedup vs baseline: 1.1582x; 1.0361x over previous
//
#include <hip/hip_runtime.h>
#include <math.h>

#define HIDDEN 1024
#define HEAD_DIM 64
#define NEXP 16
#define NTOK 8192          // B*T
#define SEQ 2048
#define NB 4

// ---------------- workspace layout (bytes) ----------------
#define OFF_PREP   0
#define OFF_CNT    256
#define OFF_TOK    512
#define OFF_WGT    (OFF_TOK + 524288)
#define OFF_RW     (OFF_WGT + 524288)
#define OFF_Q      (OFF_RW + 524288)
#define OFF_K      (OFF_Q + 2097152)
#define OFF_V      (OFF_K + 2097152)
#define OFF_ATTN   (OFF_V + 2097152)
// optional split-KV partials (only used if ws_size permits)
#define OFF_ACCP   (OFF_ATTN + 2097152)          // 4*4*2048*64 f32 = 8 MB
#define OFF_MLP    (OFF_ACCP + 8388608)          // 4*4*2048*2 f32 = 256 KB
#define WS_NEED_SPLIT (OFF_MLP + 262144)

// ---------------- prep: sim column inv-norms + sigmoid(gates) ----------------
__global__ __launch_bounds__(256) void prep_kernel(const float* __restrict__ sim,
                                                   const float* __restrict__ gates,
                                                   float* __restrict__ prep) {
    int tid = threadIdx.x;
    int e = tid & 15, part = tid >> 4;
    float ss = 0.f;
    for (int c = part; c < HIDDEN; c += 16) {
        float v = sim[c * NEXP + e];
        ss += v * v;
    }
    __shared__ float red[16][17];
    red[part][e] = ss;
    __syncthreads();
    if (tid < 16) {
        float s = 0.f;
        #pragma unroll
        for (int p = 0; p < 16; ++p) s += red[p][tid];
        prep[tid] = 1.f / fmaxf(sqrtf(s), 1e-12f);
        prep[16 + tid] = 1.f / (1.f + expf(-gates[tid]));
    }
}

// ---------------- gating: rw + expert-major lists + dense rw ----------------
__global__ __launch_bounds__(256) void gating_kernel(const float* __restrict__ h,
                                                     const float* __restrict__ sim,
                                                     const float* __restrict__ prep,
                                                     int* __restrict__ counts,
                                                     int* __restrict__ tok_list,
                                                     float* __restrict__ wgt_list,
                                                     float* __restrict__ rw_dense) {
    int t = blockIdx.x;
    int tid = threadIdx.x;
    const float* hrow = h + (size_t)t * HIDDEN;
    float dot[16];
    #pragma unroll
    for (int e = 0; e < 16; ++e) dot[e] = 0.f;
    float ss = 0.f;
    for (int c = tid; c < HIDDEN; c += 256) {
        float hv = hrow[c];
        ss += hv * hv;
        const float4* s4 = (const float4*)(sim + c * NEXP);
        float4 a = s4[0], b = s4[1], cc = s4[2], d = s4[3];
        dot[0]  += hv * a.x;  dot[1]  += hv * a.y;  dot[2]  += hv * a.z;  dot[3]  += hv * a.w;
        dot[4]  += hv * b.x;  dot[5]  += hv * b.y;  dot[6]  += hv * b.z;  dot[7]  += hv * b.w;
        dot[8]  += hv * cc.x; dot[9]  += hv * cc.y; dot[10] += hv * cc.z; dot[11] += hv * cc.w;
        dot[12] += hv * d.x;  dot[13] += hv * d.y;  dot[14] += hv * d.z;  dot[15] += hv * d.w;
    }
    int lane = tid & 63, wv = tid >> 6;
    #pragma unroll
    for (int off = 32; off > 0; off >>= 1) {
        ss += __shfl_down(ss, off, 64);
        #pragma unroll
        for (int e = 0; e < 16; ++e) dot[e] += __shfl_down(dot[e], off, 64);
    }
    __shared__ float red[4][17];
    if (lane == 0) {
        red[wv][16] = ss;
        #pragma unroll
        for (int e = 0; e < 16; ++e) red[wv][e] = dot[e];
    }
    __syncthreads();
    if (tid == 0) {
        float tss = 0.f;
        float td[16];
        #pragma unroll
        for (int e = 0; e < 16; ++e) td[e] = 0.f;
        for (int w = 0; w < 4; ++w) {
            tss += red[w][16];
            #pragma unroll
            for (int e = 0; e < 16; ++e) td[e] += red[w][e];
        }
        float invh = 1.f / fmaxf(sqrtf(tss), 1e-12f);
        float logits[16], gated[16];
        bool mask[16];
        int nact = 0;
        #pragma unroll
        for (int e = 0; e < 16; ++e) {
            logits[e] = td[e] * invh * prep[e] - prep[16 + e];
            gated[e] = fmaxf(logits[e], 0.f);
            mask[e] = logits[e] > 0.f;
            if (mask[e]) nact++;
        }
        if (nact == 0) {
            int i1 = 0; float v1 = logits[0];
            for (int e = 1; e < 16; ++e) if (logits[e] > v1) { v1 = logits[e]; i1 = e; }
            int i2 = -1; float v2 = -INFINITY;
            for (int e = 0; e < 16; ++e) if (e != i1 && logits[e] > v2) { v2 = logits[e]; i2 = e; }
            mask[i1] = true; mask[i2] = true;
        }
        float m = -INFINITY;
        #pragma unroll
        for (int e = 0; e < 16; ++e) if (mask[e]) m = fmaxf(m, gated[e]);
        float sum = 0.f;
        float p[16];
        #pragma unroll
        for (int e = 0; e < 16; ++e) {
            p[e] = mask[e] ? expf(gated[e] - m) : 0.f;
            sum += p[e];
        }
        float inv = 1.f / sum;
        for (int e = 0; e < 16; ++e) {
            if (mask[e]) {
                float w = p[e] * inv;
                rw_dense[(size_t)t * 16 + e] = w;
                int pos = atomicAdd(&counts[e], 1);
                tok_list[e * NTOK + pos] = t;
                wgt_list[e * NTOK + pos] = w;
            } else {
                rw_dense[(size_t)t * 16 + e] = 0.f;
            }
        }
    }
}

// ---------------- fused q/k/v expert GEMM v5: 128-tok chunk, 8tok/thread, K-split x2 ----------------
// grid.x = 16 experts * 64 chunks * 2 ksplit; block 256
__global__ __launch_bounds__(256) void expert_qkv_v5(const float* __restrict__ h,
                                                     const float* __restrict__ qw,
                                                     const float* __restrict__ kw,
                                                     const float* __restrict__ vw,
                                                     const int* __restrict__ counts,
                                                     const int* __restrict__ tok_list,
                                                     const float* __restrict__ wgt_list,
                                                     float* __restrict__ qb,
                                                     float* __restrict__ kb,
                                                     float* __restrict__ vb) {
    int bid = blockIdx.x;
    int e = bid >> 7, chunk = (bid >> 1) & 63, ks = bid & 1;
    int cnt = counts[e];
    int base = chunk * 128;
    if (base >= cnt) return;
    const float* W0 = qw + (size_t)e * HIDDEN * HEAD_DIM;
    const float* W1 = kw + (size_t)e * HIDDEN * HEAD_DIM;
    const float* W2 = vw + (size_t)e * HIDDEN * HEAD_DIM;

    __shared__ int s_tok[128];
    __shared__ float s_wt[128];
    __shared__ float h_s[128][20];     // [token][k] BK=16, b128 reads over k
    __shared__ float w_s[3][16][68];   // [tensor][k][d]
    int tid = threadIdx.x;
    if (tid < 128) {
        int idx = base + tid;
        s_tok[tid] = idx < cnt ? tok_list[e * NTOK + idx] : -1;
        s_wt[tid] = idx < cnt ? wgt_list[e * NTOK + idx] : 0.f;
    }
    __syncthreads();
    int tokl = tid >> 1, hf = (tid & 1) * 8;    // h staging: 128 tok x 2 halves of 8 ch
    int tg = tid >> 4, dg = tid & 15;           // compute: 8 tok x 4 d per thread
    int tok_stage = s_tok[tokl];
    const float* hrow = h + (size_t)(tok_stage >= 0 ? tok_stage : 0) * HIDDEN;

    float acc[3][8][4];
    #pragma unroll
    for (int tt = 0; tt < 3; ++tt)
        #pragma unroll
        for (int i = 0; i < 8; ++i)
            #pragma unroll
            for (int j = 0; j < 4; ++j) acc[tt][i][j] = 0.f;

    // w staging map: 768 float4 over 256 threads x 3
    int widx0 = tid, widx1 = 256 + tid, widx2 = 512 + tid;

    int koff = ks * 512;
    // prefetch tile 0
    float4 ph0 = make_float4(0.f, 0.f, 0.f, 0.f), ph1 = ph0;
    if (tok_stage >= 0) {
        ph0 = *(const float4*)&hrow[koff + hf];
        ph1 = *(const float4*)&hrow[koff + hf + 4];
    }
    float4 pw[3];
    {
        int idxs[3] = {widx0, widx1, widx2};
        #pragma unroll
        for (int r = 0; r < 3; ++r) {
            int tt = idxs[r] >> 8, rem = idxs[r] & 255;
            int k = rem >> 4, c4 = (rem & 15) * 4;
            const float* Wt = tt == 0 ? W0 : tt == 1 ? W1 : W2;
            pw[r] = *(const float4*)&Wt[(size_t)(koff + k) * HEAD_DIM + c4];
        }
    }

    for (int kt = 0; kt < 32; ++kt) {
        __syncthreads();                      // prior-tile LDS reads done
        *(float4*)&h_s[tokl][hf] = ph0;
        *(float4*)&h_s[tokl][hf + 4] = ph1;
        {
            int idxs[3] = {widx0, widx1, widx2};
            #pragma unroll
            for (int r = 0; r < 3; ++r) {
                int tt = idxs[r] >> 8, rem = idxs[r] & 255;
                int k = rem >> 4, c4 = (rem & 15) * 4;
                *(float4*)&w_s[tt][k][c4] = pw[r];
            }
        }
        __syncthreads();                      // stores visible
        if (kt < 31) {
            int kn = koff + (kt + 1) * 16;
            if (tok_stage >= 0) {
                ph0 = *(const float4*)&hrow[kn + hf];
                ph1 = *(const float4*)&hrow[kn + hf + 4];
            }
            int idxs[3] = {widx0, widx1, widx2};
            #pragma unroll
            for (int r = 0; r < 3; ++r) {
                int tt = idxs[r] >> 8, rem = idxs[r] & 255;
                int k = rem >> 4, c4 = (rem & 15) * 4;
                const float* Wt = tt == 0 ? W0 : tt == 1 ? W1 : W2;
                pw[r] = *(const float4*)&Wt[(size_t)(kn + k) * HEAD_DIM + c4];
            }
        }
        // compute: 16 k in 4 groups of 4; h read as b128 over k
        #pragma unroll
        for (int kq = 0; kq < 4; ++kq) {
            float4 h4[8];
            #pragma unroll
            for (int i = 0; i < 8; ++i) h4[i] = *(float4*)&h_s[tg * 8 + i][kq * 4];
            #pragma unroll
            for (int kk = 0; kk < 4; ++kk) {
                int k2 = kq * 4 + kk;
                float4 b0 = *(float4*)&w_s[0][k2][dg * 4];
                float4 b1 = *(float4*)&w_s[1][k2][dg * 4];
                float4 b2 = *(float4*)&w_s[2][k2][dg * 4];
                #pragma unroll
                for (int i = 0; i < 8; ++i) {
                    float a = (kk == 0) ? h4[i].x : (kk == 1) ? h4[i].y : (kk == 2) ? h4[i].z : h4[i].w;
                    acc[0][i][0] += a * b0.x; acc[0][i][1] += a * b0.y; acc[0][i][2] += a * b0.z; acc[0][i][3] += a * b0.w;
                    acc[1][i][0] += a * b1.x; acc[1][i][1] += a * b1.y; acc[1][i][2] += a * b1.z; acc[1][i][3] += a * b1.w;
                    acc[2][i][0] += a * b2.x; acc[2][i][1] += a * b2.y; acc[2][i][2] += a * b2.z; acc[2][i][3] += a * b2.w;
                }
            }
        }
    }
    // epilogue: weighted atomic scatter-add (2-way contention across ksplit)
    #pragma unroll
    for (int i = 0; i < 8; ++i) {
        int r = tg * 8 + i;
        int tok = s_tok[r];
        if (tok >= 0) {
            float wgt = s_wt[r];
            size_t off = (size_t)tok * HEAD_DIM + dg * 4;
            #pragma unroll
            for (int j = 0; j < 4; ++j) {
                atomicAdd(&qb[off + j], wgt * acc[0][i][j]);
                atomicAdd(&kb[off + j], wgt * acc[1][i][j]);
                atomicAdd(&vb[off + j], wgt * acc[2][i][j]);
            }
        }
    }
}

// ---------------- flash causal attention, split-KV, shfl softmax ----------------
// grid (64 qtiles, nchunks, 4 batches); block 256 = 32 rows x 8 lane-groups
__global__ __launch_bounds__(256) void attn_split(const float* __restrict__ q,
                                                  const float* __restrict__ k,
                                                  const float* __restrict__ v,
                                                  float* __restrict__ o,
                                                  float* __restrict__ accp,
                                                  float* __restrict__ mlp,
                                                  int nchunks) {
    int b = blockIdx.z;
    int c = blockIdx.y;
    int q0 = blockIdx.x * 32;
    int cw = (nchunks == 1) ? SEQ : 512;
    int kbeg = c * cw;
    if (kbeg > q0) return;                 // aligned: no keys for this chunk
    int kend = min(kbeg + cw, q0 + 32);    // multiple of 32
    int nkt = (kend - kbeg) >> 5;

    int tid = threadIdx.x;
    int r = tid >> 3, g = tid & 7;         // row 0..31, group 0..7 (8 contiguous lanes/row)
    int qg = q0 + r;

    __shared__ float k_s[32][68];
    __shared__ float v_s[32][68];

    // q row in regs
    float4 qv[16];
    const float* qrow = q + ((size_t)(b * SEQ + qg)) * HEAD_DIM;
    #pragma unroll
    for (int i = 0; i < 16; ++i) qv[i] = *(const float4*)(qrow + i * 4);

    float acc[8];
    #pragma unroll
    for (int i = 0; i < 8; ++i) acc[i] = 0.f;
    float m = -INFINITY, l = 0.f;

    // staging: thread stages K/V row r (of 32) cols g*8..+7 (2 float4 each)
    const float* kp = k + ((size_t)(b * SEQ + kbeg + r)) * HEAD_DIM + g * 8;
    const float* vp = v + ((size_t)(b * SEQ + kbeg + r)) * HEAD_DIM + g * 8;
    float4 pk0 = *(const float4*)kp,       pk1 = *(const float4*)(kp + 4);
    float4 pv0 = *(const float4*)vp,       pv1 = *(const float4*)(vp + 4);

    for (int kt = 0; kt < nkt; ++kt) {
        __syncthreads();                    // prior-tile LDS reads done
        *(float4*)&k_s[r][g * 8] = pk0;  *(float4*)&k_s[r][g * 8 + 4] = pk1;
        *(float4*)&v_s[r][g * 8] = pv0;  *(float4*)&v_s[r][g * 8 + 4] = pv1;
        __syncthreads();
        if (kt + 1 < nkt) {
            const float* kn = kp + (size_t)(kt + 1) * 32 * HEAD_DIM;
            const float* vn = vp + (size_t)(kt + 1) * 32 * HEAD_DIM;
            pk0 = *(const float4*)kn; pk1 = *(const float4*)(kn + 4);
            pv0 = *(const float4*)vn; pv1 = *(const float4*)(vn + 4);
        }
        // QK: this thread scores keys g*4..g*4+3 of the tile for its row
        float s[4] = {0.f, 0.f, 0.f, 0.f};
        #pragma unroll
        for (int d4 = 0; d4 < 16; ++d4) {
            float4 a = qv[d4];
            #pragma unroll
            for (int j = 0; j < 4; ++j) {
                float4 kk4 = *(float4*)&k_s[g * 4 + j][d4 * 4];
                s[j] += a.x * kk4.x + a.y * kk4.y + a.z * kk4.z + a.w * kk4.w;
            }
        }
        float pm = -INFINITY;
        #pragma unroll
        for (int j = 0; j < 4; ++j) {
            int key = kbeg + kt * 32 + g * 4 + j;
            s[j] = (key <= qg) ? s[j] * 0.125f : -INFINITY;
            pm = fmaxf(pm, s[j]);
        }
        // row reduce over 8 contiguous lanes (no LDS, no barrier)
        pm = fmaxf(pm, __shfl_xor(pm, 1, 64));
        pm = fmaxf(pm, __shfl_xor(pm, 2, 64));
        pm = fmaxf(pm, __shfl_xor(pm, 4, 64));
        float mnew = fmaxf(m, pm);          // finite: tile 0 always has key kbeg<=qg
        float corr = __expf(m - mnew);
        float p[4];
        float psum = 0.f;
        #pragma unroll
        for (int j = 0; j < 4; ++j) {
            p[j] = __expf(s[j] - mnew);
            psum += p[j];
        }
        psum += __shfl_xor(psum, 1, 64);
        psum += __shfl_xor(psum, 2, 64);
        psum += __shfl_xor(psum, 4, 64);
        l = l * corr + psum;
        m = mnew;
        #pragma unroll
        for (int d = 0; d < 8; ++d) acc[d] *= corr;
        // PV: broadcast p across the row's 8 lanes via shfl, no LDS P tile
        #pragma unroll
        for (int kk = 0; kk < 32; ++kk) {
            float pb = __shfl(p[kk & 3], (r << 3) | (kk >> 2), 64);
            float4 v0 = *(float4*)&v_s[kk][g * 8];
            float4 v1 = *(float4*)&v_s[kk][g * 8 + 4];
            acc[0] += pb * v0.x; acc[1] += pb * v0.y; acc[2] += pb * v0.z; acc[3] += pb * v0.w;
            acc[4] += pb * v1.x; acc[5] += pb * v1.y; acc[6] += pb * v1.z; acc[7] += pb * v1.w;
        }
    }

    if (nchunks == 1) {
        float invl = 1.f / l;
        float* orow = o + ((size_t)(b * SEQ + qg)) * HEAD_DIM + g * 8;
        *(float4*)orow = make_float4(acc[0] * invl, acc[1] * invl, acc[2] * invl, acc[3] * invl);
        *(float4*)(orow + 4) = make_float4(acc[4] * invl, acc[5] * invl, acc[6] * invl, acc[7] * invl);
    } else {
        size_t pidx = ((size_t)(c * NB + b) * SEQ + qg);
        float* arow = accp + pidx * HEAD_DIM + g * 8;
        *(float4*)arow = make_float4(acc[0], acc[1], acc[2], acc[3]);
        *(float4*)(arow + 4) = make_float4(acc[4], acc[5], acc[6], acc[7]);
        if (g == 0) { mlp[pidx * 2] = m; mlp[pidx * 2 + 1] = l; }
    }
}

// ---------------- combine split-KV partials ----------------
// grid 2048, block 256 = 4 rows x 64 dims
__global__ __launch_bounds__(256) void attn_combine(const float* __restrict__ accp,
                                                    const float* __restrict__ mlp,
                                                    float* __restrict__ o) {
    int gr = blockIdx.x * 4 + (threadIdx.x >> 6);   // global row 0..8191
    int d = threadIdx.x & 63;
    int b = gr >> 11, row = gr & 2047;
    int nact = (row >> 9) + 1;
    float M = -INFINITY;
    for (int c = 0; c < nact; ++c)
        M = fmaxf(M, mlp[(((size_t)(c * NB + b) * SEQ) + row) * 2]);
    float L = 0.f, A = 0.f;
    for (int c = 0; c < nact; ++c) {
        size_t pidx = ((size_t)(c * NB + b) * SEQ) + row;
        float ec = __expf(mlp[pidx * 2] - M);
        L += mlp[pidx * 2 + 1] * ec;
        A += accp[pidx * HEAD_DIM + d] * ec;
    }
    o[((size_t)(b * SEQ) + row) * HEAD_DIM + d] = A / L;
}

// ---------------- token-major output projection, LDS accumulator, NO atomics ----------------
__global__ __launch_bounds__(256) void expert_out_v2(const float* __restrict__ attn,
                                                     const float* __restrict__ ow,
                                                     const float* __restrict__ rw_dense,
                                                     float* __restrict__ out) {
    int t0 = blockIdx.x * 64;
    int c0 = blockIdx.y * 64;
    int tid = threadIdx.x;

    __shared__ float x_s[64][68];
    __shared__ float o_s[64][68];
    __shared__ float acc_s[64][68];
    __shared__ float rw_s[64][16];
    __shared__ int lst[64];
    __shared__ int lcnt;

    #pragma unroll
    for (int r = 0; r < 4; ++r) {
        int idx = r * 256 + tid;
        int t = idx >> 4, q = idx & 15;
        *(float4*)&x_s[t][q * 4] = *(const float4*)&attn[(size_t)(t0 + t) * HEAD_DIM + q * 4];
        *(float4*)&acc_s[t][q * 4] = make_float4(0.f, 0.f, 0.f, 0.f);
    }
    {
        int t = tid >> 2, eg = tid & 3;
        *(float4*)&rw_s[t][eg * 4] = *(const float4*)&rw_dense[(size_t)(t0 + t) * 16 + eg * 4];
    }
    __syncthreads();

    for (int e = 0; e < 16; ++e) {
        if (tid == 0) lcnt = 0;
        __syncthreads();
        if (tid < 64 && rw_s[tid][e] != 0.f) {
            int p = atomicAdd(&lcnt, 1);
            lst[p] = tid;
        }
        #pragma unroll
        for (int r = 0; r < 4; ++r) {
            int idx = r * 256 + tid;
            int d = idx >> 4, q = idx & 15;
            *(float4*)&o_s[d][q * 4] =
                *(const float4*)&ow[(size_t)e * HEAD_DIM * HIDDEN + (size_t)d * HIDDEN + c0 + q * 4];
        }
        __syncthreads();
        int P = lcnt;
        int pg = tid >> 4, c4 = (tid & 15) * 4;
        for (int p = pg; p < P; p += 16) {
            int t = lst[p];
            float w = rw_s[t][e];
            float sx = 0.f, sy = 0.f, sz = 0.f, sw = 0.f;
            #pragma unroll 8
            for (int d = 0; d < 64; ++d) {
                float xv = x_s[t][d];
                float4 o4 = *(float4*)&o_s[d][c4];
                sx += xv * o4.x; sy += xv * o4.y; sz += xv * o4.z; sw += xv * o4.w;
            }
            float4 a = *(float4*)&acc_s[t][c4];
            a.x += w * sx; a.y += w * sy; a.z += w * sz; a.w += w * sw;
            *(float4*)&acc_s[t][c4] = a;
        }
        __syncthreads();
    }
    #pragma unroll
    for (int r = 0; r < 4; ++r) {
        int idx = r * 256 + tid;
        int t = idx >> 4, q = idx & 15;
        *(float4*)&out[(size_t)(t0 + t) * HIDDEN + c0 + q * 4] = *(float4*)&acc_s[t][q * 4];
    }
}

extern "C" void kernel_launch(void* const* d_in, const int* in_sizes, int n_in,
                              void* d_out, int out_size, void* d_ws, size_t ws_size,
                              hipStream_t stream) {
    const float* h     = (const float*)d_in[0];
    const float* sim   = (const float*)d_in[1];
    const float* gates = (const float*)d_in[2];
    const float* qw    = (const float*)d_in[3];
    const float* kw    = (const float*)d_in[4];
    const float* vw    = (const float*)d_in[5];
    const float* ow    = (const float*)d_in[6];
    float* out = (float*)d_out;

    char* w = (char*)d_ws;
    float* prep     = (float*)(w + OFF_PREP);
    int*   counts   = (int*)(w + OFF_CNT);
    int*   tok_list = (int*)(w + OFF_TOK);
    float* wgt_list = (float*)(w + OFF_WGT);
    float* rw_dense = (float*)(w + OFF_RW);
    float* qb       = (float*)(w + OFF_Q);
    float* kb       = (float*)(w + OFF_K);
    float* vb       = (float*)(w + OFF_V);
    float* attnb    = (float*)(w + OFF_ATTN);
    float* accp     = (float*)(w + OFF_ACCP);
    float* mlp      = (float*)(w + OFF_MLP);

    hipMemsetAsync(counts, 0, 64, stream);
    hipMemsetAsync(qb, 0, 3 * 2097152, stream);   // q,k,v contiguous zero-init for atomics

    prep_kernel<<<1, 256, 0, stream>>>(sim, gates, prep);
    gating_kernel<<<NTOK, 256, 0, stream>>>(h, sim, prep, counts, tok_list, wgt_list, rw_dense);
    expert_qkv_v5<<<16 * 64 * 2, 256, 0, stream>>>(h, qw, kw, vw, counts, tok_list, wgt_list,
                                                   qb, kb, vb);
    if (ws_size >= (size_t)WS_NEED_SPLIT) {
        attn_split<<<dim3(64, 4, NB), 256, 0, stream>>>(qb, kb, vb, attnb, accp, mlp, 4);
        attn_combine<<<2048, 256, 0, stream>>>(accp, mlp, attnb);
    } else {
        attn_split<<<dim3(64, 1, NB), 256, 0, stream>>>(qb, kb, vb, attnb, attnb, attnb, 1);
    }
    expert_out_v2<<<dim3(128, 16), 256, 0, stream>>>(attnb, ow, rw_dense, out);
}

// Round 9
// 618.383 us; speedup vs baseline: 1.4321x; 1.2365x over previous
//
#include <hip/hip_runtime.h>
#include <math.h>

#define HIDDEN 1024
#define HEAD_DIM 64
#define NEXP 16
#define NTOK 8192          // B*T
#define SEQ 2048
#define NB 4

typedef short bf16x8 __attribute__((ext_vector_type(8)));
typedef float f32x4 __attribute__((ext_vector_type(4)));

// ---------------- workspace layout (bytes) ----------------
#define OFF_PREP   0
#define OFF_CNT    256
#define OFF_TOK    512
#define OFF_WGT    (OFF_TOK + 524288)
#define OFF_RW     (OFF_WGT + 524288)
#define OFF_Q      (OFF_RW + 524288)
#define OFF_K      (OFF_Q + 2097152)
#define OFF_V      (OFF_K + 2097152)
#define OFF_ATTN   (OFF_V + 2097152)
// region below is time-shared: WT bf16 (qkv phase) then attn split partials
#define OFF_ACCP   (OFF_ATTN + 2097152)          // 8 MB
#define OFF_MLP    (OFF_ACCP + 8388608)          // 256 KB
#define WS_NEED_SPLIT (OFF_MLP + 262144)
#define OFF_WT     OFF_ACCP                      // 3*16*64*1024*2 = 6.29 MB < 8 MB

__device__ __forceinline__ unsigned short f2bf(float x) {
    unsigned u = __builtin_bit_cast(unsigned, x);
    unsigned r = (u + 0x7FFFu + ((u >> 16) & 1u)) >> 16;
    return (unsigned short)r;
}

// ---------------- prep: sim column inv-norms + sigmoid(gates) ----------------
__global__ __launch_bounds__(256) void prep_kernel(const float* __restrict__ sim,
                                                   const float* __restrict__ gates,
                                                   float* __restrict__ prep) {
    int tid = threadIdx.x;
    int e = tid & 15, part = tid >> 4;
    float ss = 0.f;
    for (int c = part; c < HIDDEN; c += 16) {
        float v = sim[c * NEXP + e];
        ss += v * v;
    }
    __shared__ float red[16][17];
    red[part][e] = ss;
    __syncthreads();
    if (tid < 16) {
        float s = 0.f;
        #pragma unroll
        for (int p = 0; p < 16; ++p) s += red[p][tid];
        prep[tid] = 1.f / fmaxf(sqrtf(s), 1e-12f);
        prep[16 + tid] = 1.f / (1.f + expf(-gates[tid]));
    }
}

// ---------------- gating ----------------
__global__ __launch_bounds__(256) void gating_kernel(const float* __restrict__ h,
                                                     const float* __restrict__ sim,
                                                     const float* __restrict__ prep,
                                                     int* __restrict__ counts,
                                                     int* __restrict__ tok_list,
                                                     float* __restrict__ wgt_list,
                                                     float* __restrict__ rw_dense) {
    int t = blockIdx.x;
    int tid = threadIdx.x;
    const float* hrow = h + (size_t)t * HIDDEN;
    float dot[16];
    #pragma unroll
    for (int e = 0; e < 16; ++e) dot[e] = 0.f;
    float ss = 0.f;
    for (int c = tid; c < HIDDEN; c += 256) {
        float hv = hrow[c];
        ss += hv * hv;
        const float4* s4 = (const float4*)(sim + c * NEXP);
        float4 a = s4[0], b = s4[1], cc = s4[2], d = s4[3];
        dot[0]  += hv * a.x;  dot[1]  += hv * a.y;  dot[2]  += hv * a.z;  dot[3]  += hv * a.w;
        dot[4]  += hv * b.x;  dot[5]  += hv * b.y;  dot[6]  += hv * b.z;  dot[7]  += hv * b.w;
        dot[8]  += hv * cc.x; dot[9]  += hv * cc.y; dot[10] += hv * cc.z; dot[11] += hv * cc.w;
        dot[12] += hv * d.x;  dot[13] += hv * d.y;  dot[14] += hv * d.z;  dot[15] += hv * d.w;
    }
    int lane = tid & 63, wv = tid >> 6;
    #pragma unroll
    for (int off = 32; off > 0; off >>= 1) {
        ss += __shfl_down(ss, off, 64);
        #pragma unroll
        for (int e = 0; e < 16; ++e) dot[e] += __shfl_down(dot[e], off, 64);
    }
    __shared__ float red[4][17];
    if (lane == 0) {
        red[wv][16] = ss;
        #pragma unroll
        for (int e = 0; e < 16; ++e) red[wv][e] = dot[e];
    }
    __syncthreads();
    if (tid == 0) {
        float tss = 0.f;
        float td[16];
        #pragma unroll
        for (int e = 0; e < 16; ++e) td[e] = 0.f;
        for (int w = 0; w < 4; ++w) {
            tss += red[w][16];
            #pragma unroll
            for (int e = 0; e < 16; ++e) td[e] += red[w][e];
        }
        float invh = 1.f / fmaxf(sqrtf(tss), 1e-12f);
        float logits[16], gated[16];
        bool mask[16];
        int nact = 0;
        #pragma unroll
        for (int e = 0; e < 16; ++e) {
            logits[e] = td[e] * invh * prep[e] - prep[16 + e];
            gated[e] = fmaxf(logits[e], 0.f);
            mask[e] = logits[e] > 0.f;
            if (mask[e]) nact++;
        }
        if (nact == 0) {
            int i1 = 0; float v1 = logits[0];
            for (int e = 1; e < 16; ++e) if (logits[e] > v1) { v1 = logits[e]; i1 = e; }
            int i2 = -1; float v2 = -INFINITY;
            for (int e = 0; e < 16; ++e) if (e != i1 && logits[e] > v2) { v2 = logits[e]; i2 = e; }
            mask[i1] = true; mask[i2] = true;
        }
        float m = -INFINITY;
        #pragma unroll
        for (int e = 0; e < 16; ++e) if (mask[e]) m = fmaxf(m, gated[e]);
        float sum = 0.f;
        float p[16];
        #pragma unroll
        for (int e = 0; e < 16; ++e) {
            p[e] = mask[e] ? expf(gated[e] - m) : 0.f;
            sum += p[e];
        }
        float inv = 1.f / sum;
        for (int e = 0; e < 16; ++e) {
            if (mask[e]) {
                float w = p[e] * inv;
                rw_dense[(size_t)t * 16 + e] = w;
                int pos = atomicAdd(&counts[e], 1);
                tok_list[e * NTOK + pos] = t;
                wgt_list[e * NTOK + pos] = w;
            } else {
                rw_dense[(size_t)t * 16 + e] = 0.f;
            }
        }
    }
}

// ---------------- WT convert: fp32 W[e][k][d] -> bf16 WT[tt][e][d][k] (transposed) ----------
// grid 384: b>>7 = tt, (b>>3)&15 = e, b&7 = kt (128-k tile)
__global__ __launch_bounds__(256) void wt_convert(const float* __restrict__ qw,
                                                  const float* __restrict__ kw,
                                                  const float* __restrict__ vw,
                                                  unsigned short* __restrict__ wt) {
    int b = blockIdx.x;
    int tt = b >> 7, e = (b >> 3) & 15, kt = b & 7;
    const float* W = (tt == 0 ? qw : tt == 1 ? kw : vw) + (size_t)e * HIDDEN * HEAD_DIM;
    __shared__ unsigned short kd[128][68];
    int tid = threadIdx.x;
    // read [128 k][64 d] coalesced, cvt, store natural
    #pragma unroll
    for (int u = 0; u < 8; ++u) {
        int flat = u * 256 + tid;
        int k = flat >> 4, d4 = (flat & 15) * 4;
        float4 w4 = *(const float4*)&W[(size_t)(kt * 128 + k) * HEAD_DIM + d4];
        unsigned short b0 = f2bf(w4.x), b1 = f2bf(w4.y), b2 = f2bf(w4.z), b3 = f2bf(w4.w);
        unsigned int p0 = (unsigned int)b0 | ((unsigned int)b1 << 16);
        unsigned int p1 = (unsigned int)b2 | ((unsigned int)b3 << 16);
        *(unsigned int*)&kd[k][d4] = p0;
        *(unsigned int*)&kd[k][d4 + 2] = p1;
    }
    __syncthreads();
    // write transposed [64 d][128 k], coalesced over k
    unsigned short* wrow = wt + ((size_t)(tt * 16 + e) * HEAD_DIM) * HIDDEN + (size_t)kt * 128;
    #pragma unroll
    for (int u = 0; u < 4; ++u) {
        int flat = u * 256 + tid;
        int d = flat >> 4, k8 = (flat & 15) * 8;
        unsigned int pk[4];
        #pragma unroll
        for (int j = 0; j < 4; ++j) {
            unsigned int lo = kd[k8 + 2 * j][d];
            unsigned int hi = kd[k8 + 2 * j + 1][d];
            pk[j] = lo | (hi << 16);
        }
        *(uint4*)&wrow[(size_t)d * HIDDEN + k8] = make_uint4(pk[0], pk[1], pk[2], pk[3]);
    }
}

// ---------------- fused q/k/v expert GEMM v6: bf16 MFMA ----------------
// grid 2048: e = b>>7, chunk = b&127 (64 tokens); block 256 = 4 waves (one 16-d N-tile each)
__global__ __launch_bounds__(256) void expert_qkv_v6(const float* __restrict__ h,
                                                     const unsigned short* __restrict__ wt,
                                                     const int* __restrict__ counts,
                                                     const int* __restrict__ tok_list,
                                                     const float* __restrict__ wgt_list,
                                                     float* __restrict__ qb,
                                                     float* __restrict__ kb,
                                                     float* __restrict__ vb) {
    int e = blockIdx.x >> 7, chunk = blockIdx.x & 127;
    int cnt = counts[e];
    int base = chunk * 64;
    if (base >= cnt) return;

    __shared__ int s_tok[64];
    __shared__ float s_wt[64];
    __shared__ __align__(16) unsigned short h_s[64][72];      // [tok][k] bf16, 144B rows
    __shared__ __align__(16) unsigned short wt_s[3][64][72];  // [tt][d][k] bf16

    int tid = threadIdx.x;
    int lane = tid & 63, wv = tid >> 6;
    if (tid < 64) {
        int idx = base + tid;
        s_tok[tid] = idx < cnt ? tok_list[e * NTOK + idx] : -1;
        s_wt[tid] = idx < cnt ? wgt_list[e * NTOK + idx] : 0.f;
    }
    __syncthreads();

    // staging maps
    int stok = tid >> 2, skq = (tid & 3) * 16;       // h: 64 tok x 16 k per thread
    int tok_stage = s_tok[stok];
    const float* hrow = h + (size_t)(tok_stage >= 0 ? tok_stage : 0) * HIDDEN;
    const unsigned short* wbase = wt + (size_t)e * HEAD_DIM * HIDDEN;

    f32x4 acc[3][4];
    #pragma unroll
    for (int tt = 0; tt < 3; ++tt)
        #pragma unroll
        for (int mt = 0; mt < 4; ++mt)
            acc[tt][mt] = (f32x4){0.f, 0.f, 0.f, 0.f};

    // prefetch step 0
    float4 ph[4];
    uint4 pwt[6];
    {
        #pragma unroll
        for (int r = 0; r < 4; ++r) {
            ph[r] = make_float4(0.f, 0.f, 0.f, 0.f);
            if (tok_stage >= 0) ph[r] = *(const float4*)&hrow[skq + r * 4];
        }
        #pragma unroll
        for (int i = 0; i < 6; ++i) {
            int flat = i * 256 + tid;
            int ttx = flat >> 9, rem = flat & 511;
            int d = rem >> 3, k8 = (rem & 7) * 8;
            pwt[i] = *(const uint4*)&wbase[((size_t)ttx * 16 * HEAD_DIM + d) * HIDDEN + k8];
        }
    }

    for (int step = 0; step < 16; ++step) {
        __syncthreads();                  // prior-step LDS reads done
        // store h (cvt to bf16)
        {
            unsigned int pk[8];
            const float* f = (const float*)ph;
            #pragma unroll
            for (int j = 0; j < 8; ++j)
                pk[j] = (unsigned int)f2bf(f[2 * j]) | ((unsigned int)f2bf(f[2 * j + 1]) << 16);
            *(uint4*)&h_s[stok][skq] = make_uint4(pk[0], pk[1], pk[2], pk[3]);
            *(uint4*)&h_s[stok][skq + 8] = make_uint4(pk[4], pk[5], pk[6], pk[7]);
        }
        // store wt (already bf16)
        #pragma unroll
        for (int i = 0; i < 6; ++i) {
            int flat = i * 256 + tid;
            int ttx = flat >> 9, rem = flat & 511;
            int d = rem >> 3, k8 = (rem & 7) * 8;
            *(uint4*)&wt_s[ttx][d][k8] = pwt[i];
        }
        __syncthreads();
        // prefetch next step
        if (step < 15) {
            int koff = (step + 1) * 64;
            #pragma unroll
            for (int r = 0; r < 4; ++r) {
                if (tok_stage >= 0) ph[r] = *(const float4*)&hrow[koff + skq + r * 4];
            }
            #pragma unroll
            for (int i = 0; i < 6; ++i) {
                int flat = i * 256 + tid;
                int ttx = flat >> 9, rem = flat & 511;
                int d = rem >> 3, k8 = (rem & 7) * 8;
                pwt[i] = *(const uint4*)&wbase[((size_t)ttx * 16 * HEAD_DIM + d) * HIDDEN + koff + k8];
            }
        }
        // compute: 2 substeps of K=32
        #pragma unroll
        for (int ks = 0; ks < 2; ++ks) {
            int kf = ks * 32 + (lane >> 4) * 8;
            bf16x8 a[4], bfr[3];
            #pragma unroll
            for (int mt = 0; mt < 4; ++mt)
                a[mt] = *(const bf16x8*)&h_s[mt * 16 + (lane & 15)][kf];
            #pragma unroll
            for (int tt = 0; tt < 3; ++tt)
                bfr[tt] = *(const bf16x8*)&wt_s[tt][wv * 16 + (lane & 15)][kf];
            #pragma unroll
            for (int tt = 0; tt < 3; ++tt)
                #pragma unroll
                for (int mt = 0; mt < 4; ++mt)
                    acc[tt][mt] = __builtin_amdgcn_mfma_f32_16x16x32_bf16(a[mt], bfr[tt],
                                                                          acc[tt][mt], 0, 0, 0);
        }
    }

    // epilogue: C/D layout col=lane&15, row=(lane>>4)*4+reg  [verified m89]
    int dcol = wv * 16 + (lane & 15);
    #pragma unroll
    for (int mt = 0; mt < 4; ++mt) {
        #pragma unroll
        for (int r = 0; r < 4; ++r) {
            int rl = mt * 16 + (lane >> 4) * 4 + r;
            int tok = s_tok[rl];
            if (tok >= 0) {
                float wgt = s_wt[rl];
                size_t off = (size_t)tok * HEAD_DIM + dcol;
                atomicAdd(&qb[off], wgt * acc[0][mt][r]);
                atomicAdd(&kb[off], wgt * acc[1][mt][r]);
                atomicAdd(&vb[off], wgt * acc[2][mt][r]);
            }
        }
    }
}

// ---------------- fp32 fallback (proven r8 path) ----------------
__global__ __launch_bounds__(256) void expert_qkv_v5(const float* __restrict__ h,
                                                     const float* __restrict__ qw,
                                                     const float* __restrict__ kw,
                                                     const float* __restrict__ vw,
                                                     const int* __restrict__ counts,
                                                     const int* __restrict__ tok_list,
                                                     const float* __restrict__ wgt_list,
                                                     float* __restrict__ qb,
                                                     float* __restrict__ kb,
                                                     float* __restrict__ vb) {
    int bid = blockIdx.x;
    int e = bid >> 7, chunk = (bid >> 1) & 63, ks = bid & 1;
    int cnt = counts[e];
    int base = chunk * 128;
    if (base >= cnt) return;
    const float* W0 = qw + (size_t)e * HIDDEN * HEAD_DIM;
    const float* W1 = kw + (size_t)e * HIDDEN * HEAD_DIM;
    const float* W2 = vw + (size_t)e * HIDDEN * HEAD_DIM;

    __shared__ int s_tok[128];
    __shared__ float s_wt[128];
    __shared__ float h_s[128][20];
    __shared__ float w_s[3][16][68];
    int tid = threadIdx.x;
    if (tid < 128) {
        int idx = base + tid;
        s_tok[tid] = idx < cnt ? tok_list[e * NTOK + idx] : -1;
        s_wt[tid] = idx < cnt ? wgt_list[e * NTOK + idx] : 0.f;
    }
    __syncthreads();
    int tokl = tid >> 1, hf = (tid & 1) * 8;
    int tg = tid >> 4, dg = tid & 15;
    int tok_stage = s_tok[tokl];
    const float* hrow = h + (size_t)(tok_stage >= 0 ? tok_stage : 0) * HIDDEN;

    float acc[3][8][4];
    #pragma unroll
    for (int tt = 0; tt < 3; ++tt)
        #pragma unroll
        for (int i = 0; i < 8; ++i)
            #pragma unroll
            for (int j = 0; j < 4; ++j) acc[tt][i][j] = 0.f;

    int widx0 = tid, widx1 = 256 + tid, widx2 = 512 + tid;
    int koff = ks * 512;
    float4 ph0 = make_float4(0.f, 0.f, 0.f, 0.f), ph1 = ph0;
    if (tok_stage >= 0) {
        ph0 = *(const float4*)&hrow[koff + hf];
        ph1 = *(const float4*)&hrow[koff + hf + 4];
    }
    float4 pw[3];
    {
        int idxs[3] = {widx0, widx1, widx2};
        #pragma unroll
        for (int r = 0; r < 3; ++r) {
            int tt = idxs[r] >> 8, rem = idxs[r] & 255;
            int k = rem >> 4, c4 = (rem & 15) * 4;
            const float* Wt = tt == 0 ? W0 : tt == 1 ? W1 : W2;
            pw[r] = *(const float4*)&Wt[(size_t)(koff + k) * HEAD_DIM + c4];
        }
    }

    for (int kt = 0; kt < 32; ++kt) {
        __syncthreads();
        *(float4*)&h_s[tokl][hf] = ph0;
        *(float4*)&h_s[tokl][hf + 4] = ph1;
        {
            int idxs[3] = {widx0, widx1, widx2};
            #pragma unroll
            for (int r = 0; r < 3; ++r) {
                int tt = idxs[r] >> 8, rem = idxs[r] & 255;
                int k = rem >> 4, c4 = (rem & 15) * 4;
                *(float4*)&w_s[tt][k][c4] = pw[r];
            }
        }
        __syncthreads();
        if (kt < 31) {
            int kn = koff + (kt + 1) * 16;
            if (tok_stage >= 0) {
                ph0 = *(const float4*)&hrow[kn + hf];
                ph1 = *(const float4*)&hrow[kn + hf + 4];
            }
            int idxs[3] = {widx0, widx1, widx2};
            #pragma unroll
            for (int r = 0; r < 3; ++r) {
                int tt = idxs[r] >> 8, rem = idxs[r] & 255;
                int k = rem >> 4, c4 = (rem & 15) * 4;
                const float* Wt = tt == 0 ? W0 : tt == 1 ? W1 : W2;
                pw[r] = *(const float4*)&Wt[(size_t)(kn + k) * HEAD_DIM + c4];
            }
        }
        #pragma unroll
        for (int kq = 0; kq < 4; ++kq) {
            float4 h4[8];
            #pragma unroll
            for (int i = 0; i < 8; ++i) h4[i] = *(float4*)&h_s[tg * 8 + i][kq * 4];
            #pragma unroll
            for (int kk = 0; kk < 4; ++kk) {
                int k2 = kq * 4 + kk;
                float4 b0 = *(float4*)&w_s[0][k2][dg * 4];
                float4 b1 = *(float4*)&w_s[1][k2][dg * 4];
                float4 b2 = *(float4*)&w_s[2][k2][dg * 4];
                #pragma unroll
                for (int i = 0; i < 8; ++i) {
                    float a = (kk == 0) ? h4[i].x : (kk == 1) ? h4[i].y : (kk == 2) ? h4[i].z : h4[i].w;
                    acc[0][i][0] += a * b0.x; acc[0][i][1] += a * b0.y; acc[0][i][2] += a * b0.z; acc[0][i][3] += a * b0.w;
                    acc[1][i][0] += a * b1.x; acc[1][i][1] += a * b1.y; acc[1][i][2] += a * b1.z; acc[1][i][3] += a * b1.w;
                    acc[2][i][0] += a * b2.x; acc[2][i][1] += a * b2.y; acc[2][i][2] += a * b2.z; acc[2][i][3] += a * b2.w;
                }
            }
        }
    }
    #pragma unroll
    for (int i = 0; i < 8; ++i) {
        int r = tg * 8 + i;
        int tok = s_tok[r];
        if (tok >= 0) {
            float wgt = s_wt[r];
            size_t off = (size_t)tok * HEAD_DIM + dg * 4;
            #pragma unroll
            for (int j = 0; j < 4; ++j) {
                atomicAdd(&qb[off + j], wgt * acc[0][i][j]);
                atomicAdd(&kb[off + j], wgt * acc[1][i][j]);
                atomicAdd(&vb[off + j], wgt * acc[2][i][j]);
            }
        }
    }
}

// ---------------- flash causal attention, split-KV, shfl softmax ----------------
__global__ __launch_bounds__(256) void attn_split(const float* __restrict__ q,
                                                  const float* __restrict__ k,
                                                  const float* __restrict__ v,
                                                  float* __restrict__ o,
                                                  float* __restrict__ accp,
                                                  float* __restrict__ mlp,
                                                  int nchunks) {
    int b = blockIdx.z;
    int c = blockIdx.y;
    int q0 = blockIdx.x * 32;
    int cw = (nchunks == 1) ? SEQ : 512;
    int kbeg = c * cw;
    if (kbeg > q0) return;
    int kend = min(kbeg + cw, q0 + 32);
    int nkt = (kend - kbeg) >> 5;

    int tid = threadIdx.x;
    int r = tid >> 3, g = tid & 7;
    int qg = q0 + r;

    __shared__ float k_s[32][68];
    __shared__ float v_s[32][68];

    float4 qv[16];
    const float* qrow = q + ((size_t)(b * SEQ + qg)) * HEAD_DIM;
    #pragma unroll
    for (int i = 0; i < 16; ++i) qv[i] = *(const float4*)(qrow + i * 4);

    float acc[8];
    #pragma unroll
    for (int i = 0; i < 8; ++i) acc[i] = 0.f;
    float m = -INFINITY, l = 0.f;

    const float* kp = k + ((size_t)(b * SEQ + kbeg + r)) * HEAD_DIM + g * 8;
    const float* vp = v + ((size_t)(b * SEQ + kbeg + r)) * HEAD_DIM + g * 8;
    float4 pk0 = *(const float4*)kp,       pk1 = *(const float4*)(kp + 4);
    float4 pv0 = *(const float4*)vp,       pv1 = *(const float4*)(vp + 4);

    for (int kt = 0; kt < nkt; ++kt) {
        __syncthreads();
        *(float4*)&k_s[r][g * 8] = pk0;  *(float4*)&k_s[r][g * 8 + 4] = pk1;
        *(float4*)&v_s[r][g * 8] = pv0;  *(float4*)&v_s[r][g * 8 + 4] = pv1;
        __syncthreads();
        if (kt + 1 < nkt) {
            const float* kn = kp + (size_t)(kt + 1) * 32 * HEAD_DIM;
            const float* vn = vp + (size_t)(kt + 1) * 32 * HEAD_DIM;
            pk0 = *(const float4*)kn; pk1 = *(const float4*)(kn + 4);
            pv0 = *(const float4*)vn; pv1 = *(const float4*)(vn + 4);
        }
        float s[4] = {0.f, 0.f, 0.f, 0.f};
        #pragma unroll
        for (int d4 = 0; d4 < 16; ++d4) {
            float4 a = qv[d4];
            #pragma unroll
            for (int j = 0; j < 4; ++j) {
                float4 kk4 = *(float4*)&k_s[g * 4 + j][d4 * 4];
                s[j] += a.x * kk4.x + a.y * kk4.y + a.z * kk4.z + a.w * kk4.w;
            }
        }
        float pm = -INFINITY;
        #pragma unroll
        for (int j = 0; j < 4; ++j) {
            int key = kbeg + kt * 32 + g * 4 + j;
            s[j] = (key <= qg) ? s[j] * 0.125f : -INFINITY;
            pm = fmaxf(pm, s[j]);
        }
        pm = fmaxf(pm, __shfl_xor(pm, 1, 64));
        pm = fmaxf(pm, __shfl_xor(pm, 2, 64));
        pm = fmaxf(pm, __shfl_xor(pm, 4, 64));
        float mnew = fmaxf(m, pm);
        float corr = __expf(m - mnew);
        float p[4];
        float psum = 0.f;
        #pragma unroll
        for (int j = 0; j < 4; ++j) {
            p[j] = __expf(s[j] - mnew);
            psum += p[j];
        }
        psum += __shfl_xor(psum, 1, 64);
        psum += __shfl_xor(psum, 2, 64);
        psum += __shfl_xor(psum, 4, 64);
        l = l * corr + psum;
        m = mnew;
        #pragma unroll
        for (int d = 0; d < 8; ++d) acc[d] *= corr;
        #pragma unroll
        for (int kk = 0; kk < 32; ++kk) {
            float pb = __shfl(p[kk & 3], (r << 3) | (kk >> 2), 64);
            float4 v0 = *(float4*)&v_s[kk][g * 8];
            float4 v1 = *(float4*)&v_s[kk][g * 8 + 4];
            acc[0] += pb * v0.x; acc[1] += pb * v0.y; acc[2] += pb * v0.z; acc[3] += pb * v0.w;
            acc[4] += pb * v1.x; acc[5] += pb * v1.y; acc[6] += pb * v1.z; acc[7] += pb * v1.w;
        }
    }

    if (nchunks == 1) {
        float invl = 1.f / l;
        float* orow = o + ((size_t)(b * SEQ + qg)) * HEAD_DIM + g * 8;
        *(float4*)orow = make_float4(acc[0] * invl, acc[1] * invl, acc[2] * invl, acc[3] * invl);
        *(float4*)(orow + 4) = make_float4(acc[4] * invl, acc[5] * invl, acc[6] * invl, acc[7] * invl);
    } else {
        size_t pidx = ((size_t)(c * NB + b) * SEQ + qg);
        float* arow = accp + pidx * HEAD_DIM + g * 8;
        *(float4*)arow = make_float4(acc[0], acc[1], acc[2], acc[3]);
        *(float4*)(arow + 4) = make_float4(acc[4], acc[5], acc[6], acc[7]);
        if (g == 0) { mlp[pidx * 2] = m; mlp[pidx * 2 + 1] = l; }
    }
}

// ---------------- combine split-KV partials ----------------
__global__ __launch_bounds__(256) void attn_combine(const float* __restrict__ accp,
                                                    const float* __restrict__ mlp,
                                                    float* __restrict__ o) {
    int gr = blockIdx.x * 4 + (threadIdx.x >> 6);
    int d = threadIdx.x & 63;
    int b = gr >> 11, row = gr & 2047;
    int nact = (row >> 9) + 1;
    float M = -INFINITY;
    for (int c = 0; c < nact; ++c)
        M = fmaxf(M, mlp[(((size_t)(c * NB + b) * SEQ) + row) * 2]);
    float L = 0.f, A = 0.f;
    for (int c = 0; c < nact; ++c) {
        size_t pidx = ((size_t)(c * NB + b) * SEQ) + row;
        float ec = __expf(mlp[pidx * 2] - M);
        L += mlp[pidx * 2 + 1] * ec;
        A += accp[pidx * HEAD_DIM + d] * ec;
    }
    o[((size_t)(b * SEQ) + row) * HEAD_DIM + d] = A / L;
}

// ---------------- token-major output projection, LDS accumulator, NO atomics ----------------
__global__ __launch_bounds__(256) void expert_out_v2(const float* __restrict__ attn,
                                                     const float* __restrict__ ow,
                                                     const float* __restrict__ rw_dense,
                                                     float* __restrict__ out) {
    int t0 = blockIdx.x * 64;
    int c0 = blockIdx.y * 64;
    int tid = threadIdx.x;

    __shared__ float x_s[64][68];
    __shared__ float o_s[64][68];
    __shared__ float acc_s[64][68];
    __shared__ float rw_s[64][16];
    __shared__ int lst[64];
    __shared__ int lcnt;

    #pragma unroll
    for (int r = 0; r < 4; ++r) {
        int idx = r * 256 + tid;
        int t = idx >> 4, q = idx & 15;
        *(float4*)&x_s[t][q * 4] = *(const float4*)&attn[(size_t)(t0 + t) * HEAD_DIM + q * 4];
        *(float4*)&acc_s[t][q * 4] = make_float4(0.f, 0.f, 0.f, 0.f);
    }
    {
        int t = tid >> 2, eg = tid & 3;
        *(float4*)&rw_s[t][eg * 4] = *(const float4*)&rw_dense[(size_t)(t0 + t) * 16 + eg * 4];
    }
    __syncthreads();

    for (int e = 0; e < 16; ++e) {
        if (tid == 0) lcnt = 0;
        __syncthreads();
        if (tid < 64 && rw_s[tid][e] != 0.f) {
            int p = atomicAdd(&lcnt, 1);
            lst[p] = tid;
        }
        #pragma unroll
        for (int r = 0; r < 4; ++r) {
            int idx = r * 256 + tid;
            int d = idx >> 4, q = idx & 15;
            *(float4*)&o_s[d][q * 4] =
                *(const float4*)&ow[(size_t)e * HEAD_DIM * HIDDEN + (size_t)d * HIDDEN + c0 + q * 4];
        }
        __syncthreads();
        int P = lcnt;
        int pg = tid >> 4, c4 = (tid & 15) * 4;
        for (int p = pg; p < P; p += 16) {
            int t = lst[p];
            float w = rw_s[t][e];
            float sx = 0.f, sy = 0.f, sz = 0.f, sw = 0.f;
            #pragma unroll 8
            for (int d = 0; d < 64; ++d) {
                float xv = x_s[t][d];
                float4 o4 = *(float4*)&o_s[d][c4];
                sx += xv * o4.x; sy += xv * o4.y; sz += xv * o4.z; sw += xv * o4.w;
            }
            float4 a = *(float4*)&acc_s[t][c4];
            a.x += w * sx; a.y += w * sy; a.z += w * sz; a.w += w * sw;
            *(float4*)&acc_s[t][c4] = a;
        }
        __syncthreads();
    }
    #pragma unroll
    for (int r = 0; r < 4; ++r) {
        int idx = r * 256 + tid;
        int t = idx >> 4, q = idx & 15;
        *(float4*)&out[(size_t)(t0 + t) * HIDDEN + c0 + q * 4] = *(float4*)&acc_s[t][q * 4];
    }
}

extern "C" void kernel_launch(void* const* d_in, const int* in_sizes, int n_in,
                              void* d_out, int out_size, void* d_ws, size_t ws_size,
                              hipStream_t stream) {
    const float* h     = (const float*)d_in[0];
    const float* sim   = (const float*)d_in[1];
    const float* gates = (const float*)d_in[2];
    const float* qw    = (const float*)d_in[3];
    const float* kw    = (const float*)d_in[4];
    const float* vw    = (const float*)d_in[5];
    const float* ow    = (const float*)d_in[6];
    float* out = (float*)d_out;

    char* w = (char*)d_ws;
    float* prep     = (float*)(w + OFF_PREP);
    int*   counts   = (int*)(w + OFF_CNT);
    int*   tok_list = (int*)(w + OFF_TOK);
    float* wgt_list = (float*)(w + OFF_WGT);
    float* rw_dense = (float*)(w + OFF_RW);
    float* qb       = (float*)(w + OFF_Q);
    float* kb       = (float*)(w + OFF_K);
    float* vb       = (float*)(w + OFF_V);
    float* attnb    = (float*)(w + OFF_ATTN);
    float* accp     = (float*)(w + OFF_ACCP);
    float* mlp      = (float*)(w + OFF_MLP);
    unsigned short* wtb = (unsigned short*)(w + OFF_WT);

    hipMemsetAsync(counts, 0, 64, stream);
    hipMemsetAsync(qb, 0, 3 * 2097152, stream);   // q,k,v zero-init for atomics

    prep_kernel<<<1, 256, 0, stream>>>(sim, gates, prep);
    gating_kernel<<<NTOK, 256, 0, stream>>>(h, sim, prep, counts, tok_list, wgt_list, rw_dense);

    bool big_ws = ws_size >= (size_t)WS_NEED_SPLIT;
    if (big_ws) {
        wt_convert<<<384, 256, 0, stream>>>(qw, kw, vw, wtb);
        expert_qkv_v6<<<16 * 128, 256, 0, stream>>>(h, wtb, counts, tok_list, wgt_list,
                                                    qb, kb, vb);
    } else {
        expert_qkv_v5<<<16 * 64 * 2, 256, 0, stream>>>(h, qw, kw, vw, counts, tok_list,
                                                       wgt_list, qb, kb, vb);
    }
    if (big_ws) {
        attn_split<<<dim3(64, 4, NB), 256, 0, stream>>>(qb, kb, vb, attnb, accp, mlp, 4);
        attn_combine<<<2048, 256, 0, stream>>>(accp, mlp, attnb);
    } else {
        attn_split<<<dim3(64, 1, NB), 256, 0, stream>>>(qb, kb, vb, attnb, attnb, attnb, 1);
    }
    expert_out_v2<<<dim3(128, 16), 256, 0, stream>>>(attnb, ow, rw_dense, out);
}